// Round 7
// baseline (424.573 us; speedup 1.0000x reference)
//
#include <hip/hip_runtime.h>
#include <hip/hip_bf16.h>
#include <math.h>

// B=2 S=2048 D=1024 H=16 DH=64 F=4096. ALL inputs/outputs fp32.
// Internals bf16 (MFMA) with fp32 accumulate; residual stream fp32 in d_out.
// Workspace (64 MiB):
//   [0,6)   Wqkv_b  [6,8) Wout_b  [8,16) W1_b  [16,24) W2_b  (contiguous: cvt4)
//   [24,32) h (LN outputs)
//   [32,48) qk [4096][2048] bf16   [48,56) vt [32][64][2048] bf16 V^T
//   [56,64) attn [4096][1024] bf16
//   [32,64) act [4096][4096] bf16 (FFN, aliases qk/vt/attn after attention)
//   x2 fp32 = d_out (out-proj writes; LN2 reads; FFN2 atomicAdds in place)
//
// Round 7: ring-3 (r2/r5-verified, the only structure that beat 2-buf:
// FFN1 95->75) becomes the ONLY GEMM engine — out-proj and FFN2 move onto
// it. flash_attn gets the T14 async-STAGE split (regs early, LDS-write late).

typedef __bf16 bf16;
typedef __bf16 bf16x4 __attribute__((ext_vector_type(4)));
typedef __bf16 bf16x8 __attribute__((ext_vector_type(8)));
typedef float f32x4 __attribute__((ext_vector_type(4)));

#define LOG2E 1.4426950408889634f
#define NSHIFT -17.312340489f   // -12 * log2(e): fixed softmax shift of 12

__device__ __forceinline__ f32x4 mfma16(bf16x8 a, bf16x8 b, f32x4 c) {
    return __builtin_amdgcn_mfma_f32_16x16x32_bf16(a, b, c, 0, 0, 0);
}
// async global->LDS, 16B per lane; LDS dest = wave-uniform base + lane*16
__device__ __forceinline__ void load16_lds(const bf16* g, bf16* l) {
    __builtin_amdgcn_global_load_lds(
        (__attribute__((address_space(1))) void*)g,
        (__attribute__((address_space(3))) void*)l, 16, 0, 0);
}

// ---------------------------------------------------------------------------
// All four weight tensors fp32 -> bf16 in one launch; dst regions contiguous.
// ---------------------------------------------------------------------------
__global__ __launch_bounds__(256) void cvt4_kernel(const float* __restrict__ s0,
                                                   const float* __restrict__ s1,
                                                   const float* __restrict__ s2,
                                                   const float* __restrict__ s3,
                                                   bf16* __restrict__ dst) {
    const int blk = blockIdx.x;
    const float* s;
    int base;
    if (blk < 3072)      { s = s0; base = blk * 1024; }
    else if (blk < 4096) { s = s1; base = (blk - 3072) * 1024; }
    else if (blk < 8192) { s = s2; base = (blk - 4096) * 1024; }
    else                 { s = s3; base = (blk - 8192) * 1024; }
    const int t4 = threadIdx.x * 4;
    const float4 f = *(const float4*)(s + base + t4);
    bf16x4 o;
    o[0] = (bf16)f.x; o[1] = (bf16)f.y; o[2] = (bf16)f.z; o[3] = (bf16)f.w;
    *(bf16x4*)(dst + (size_t)blk * 1024 + t4) = o;
}

// ---------------------------------------------------------------------------
// LayerNorm row of 1024: fp32 in -> bf16 out. (x-mean)/(sqrt(var)+eps)
// ---------------------------------------------------------------------------
__global__ __launch_bounds__(256) void ln_kernel(const float* __restrict__ xin,
                                                 bf16* __restrict__ out,
                                                 const float* __restrict__ gamma,
                                                 const float* __restrict__ beta) {
    const int row = blockIdx.x;
    const int tid = threadIdx.x;
    const float4 f = *(const float4*)(xin + (size_t)row * 1024 + tid * 4);
    float v[4] = {f.x, f.y, f.z, f.w};
    float s = v[0] + v[1] + v[2] + v[3];
    float s2 = v[0] * v[0] + v[1] * v[1] + v[2] * v[2] + v[3] * v[3];
#pragma unroll
    for (int off = 1; off < 64; off <<= 1) {
        s += __shfl_xor(s, off);
        s2 += __shfl_xor(s2, off);
    }
    __shared__ float red[8];
    const int wave = tid >> 6, lane = tid & 63;
    if (lane == 0) { red[wave] = s; red[4 + wave] = s2; }
    __syncthreads();
    s = red[0] + red[1] + red[2] + red[3];
    s2 = red[4] + red[5] + red[6] + red[7];
    const float mean = s * (1.0f / 1024.0f);
    float var = s2 * (1.0f / 1024.0f) - mean * mean;
    var = fmaxf(var, 0.0f);
    const float rstd = 1.0f / (sqrtf(var) + 1e-6f);
    const int c = tid * 4;
    const float4 g = *(const float4*)(gamma + c);
    const float4 b = *(const float4*)(beta + c);
    bf16x4 o;
    o[0] = (bf16)((v[0] - mean) * rstd * g.x + b.x);
    o[1] = (bf16)((v[1] - mean) * rstd * g.y + b.y);
    o[2] = (bf16)((v[2] - mean) * rstd * g.z + b.z);
    o[3] = (bf16)((v[3] - mean) * rstd * g.w + b.w);
    *(bf16x4*)(out + (size_t)row * 1024 + c) = o;
}

// ---------------------------------------------------------------------------
// gemm_r3: RING-3 LDS 128x128/BK=32 (r2/r5-verified body; FFN1 75us,
// MfmaUtil 17.5, 0 bank conflicts). Single GEMM engine for all four GEMMs.
//   iter t: issue STAGE(t+2) -> ds_read/MFMA tile t -> s_waitcnt vmcnt(4)
//   (t+1's loads, issued a full iteration earlier, must have retired;
//   t+2's 4 loads stay in flight) -> raw s_barrier. Never vmcnt(0) in the
//   main loop (T4). Raw s_barrier: __syncthreads would re-insert vmcnt(0).
// XOR bank swizzle: staging (row, slot c) fetches global chunk
// c ^ ((row>>1)&3); readers fetch phys chunk quad ^ ((row>>1)&3) -> 0
// conflicts (verified).
// EPI: 1=+fp32 res -> fp32   2=+bias,GELU -> bf16
//      4=qkv split store (qk + vt)   5=atomicAdd fp32 (+bias if kz==0)
// ---------------------------------------------------------------------------
#define STAGE(tt, bi)                                              \
    do {                                                           \
        const int _k0 = (tt) << 5;                                 \
        load16_lds(Ap + _k0, &As[bi][tid * 8]);                    \
        load16_lds(Bp + _k0, &Bs[bi][tid * 8]);                    \
        load16_lds(Ap + rstep + _k0, &As[bi][tid * 8 + 2048]);     \
        load16_lds(Bp + rstep + _k0, &Bs[bi][tid * 8 + 2048]);     \
    } while (0)

template <int EPI>
__global__ __launch_bounds__(256, 3) void gemm_r3(const bf16* __restrict__ A,
                                                  const bf16* __restrict__ B,
                                                  int N, int K, int ldk,
                                                  bf16* __restrict__ outb,
                                                  float* __restrict__ outf,
                                                  const float* __restrict__ bias,
                                                  const float* __restrict__ resf,
                                                  bf16* __restrict__ qk,
                                                  bf16* __restrict__ vt) {
    __shared__ alignas(16) bf16 As[3][128 * 32];
    __shared__ alignas(16) bf16 Bs[3][128 * 32];
    const int tid = threadIdx.x;
    const int bm = blockIdx.x, bn = blockIdx.y;
    const int wave = tid >> 6, lane = tid & 63;
    const int wm = (wave >> 1) * 64, wn = (wave & 1) * 64;
    const int l16 = lane & 15, quad = lane >> 4;

    f32x4 acc[4][4] = {};

    const size_t koff = (size_t)blockIdx.z * K;
    const int row0 = tid >> 2, ch0 = tid & 3;
    const int gch = ch0 ^ ((row0 >> 1) & 3);
    const bf16* Ap = A + (size_t)(bm * 128 + row0) * ldk + koff + gch * 8;
    const bf16* Bp = B + (size_t)(bn * 128 + row0) * ldk + koff + gch * 8;
    const size_t rstep = (size_t)64 * ldk;

    const int nt = K >> 5;                   // BK=32 K-steps (>= 3 always here)

    STAGE(0, 0);
    STAGE(1, 1);
    asm volatile("s_waitcnt vmcnt(4)" ::: "memory");
    __builtin_amdgcn_s_barrier();
    asm volatile("" ::: "memory");

    int i0 = 0, i1 = 1, i2 = 2;              // ring: i0=compute, i2=stage dest
    for (int t = 0; t < nt; ++t) {
        if (t + 2 < nt) STAGE(t + 2, i2);    // issue-early: 2-iter window

        bf16x8 af[4], bfr[4];
#pragma unroll
        for (int i = 0; i < 4; i++) {
            const int ra = wm + i * 16 + l16;
            af[i] = *(const bf16x8*)(&As[i0][ra * 32 + (quad ^ ((ra >> 1) & 3)) * 8]);
        }
#pragma unroll
        for (int j = 0; j < 4; j++) {
            const int rb = wn + j * 16 + l16;
            bfr[j] = *(const bf16x8*)(&Bs[i0][rb * 32 + (quad ^ ((rb >> 1) & 3)) * 8]);
        }
        __builtin_amdgcn_s_setprio(1);
#pragma unroll
        for (int i = 0; i < 4; i++)
#pragma unroll
            for (int j = 0; j < 4; j++) acc[i][j] = mfma16(af[i], bfr[j], acc[i][j]);
        __builtin_amdgcn_s_setprio(0);

        if (t + 2 < nt) {
            asm volatile("s_waitcnt vmcnt(4)" ::: "memory");
        } else if (t + 1 < nt) {
            asm volatile("s_waitcnt vmcnt(0)" ::: "memory");
        }
        if (t + 1 < nt) {
            __builtin_amdgcn_s_barrier();
            asm volatile("" ::: "memory");
        }
        const int tmp = i0; i0 = i1; i1 = i2; i2 = tmp;
    }

#pragma unroll
    for (int i = 0; i < 4; i++) {
#pragma unroll
        for (int j = 0; j < 4; j++) {
            const int gr0 = bm * 128 + wm + i * 16 + quad * 4;
            const int gc = bn * 128 + wn + j * 16 + l16;
            float bv = 0.0f;
            if (EPI == 2) bv = bias[gc];
            if (EPI == 5 && bias && blockIdx.z == 0) bv = bias[gc];
            if (EPI == 4 && gc >= 2048) {
                // V part -> vt[b][h][d][s], packed over 4 consecutive s
                const int n = gc - 2048;
                const int hh = n >> 6, dd = n & 63;
                const int bb = gr0 >> 11, ss = gr0 & 2047;
                bf16x4 pk;
#pragma unroll
                for (int r = 0; r < 4; r++) pk[r] = (bf16)acc[i][j][r];
                *(bf16x4*)(vt + ((size_t)((bb * 16 + hh) * 64 + dd)) * 2048 + ss) = pk;
            } else {
#pragma unroll
                for (int r = 0; r < 4; r++) {
                    const float v = acc[i][j][r];
                    const size_t idx = (size_t)(gr0 + r) * N + gc;
                    if (EPI == 1) {
                        outf[idx] = v + resf[idx];
                    } else if (EPI == 2) {
                        const float t = v + bv;
                        outb[idx] = (bf16)(0.5f * t * (1.0f + erff(t * 0.70710678118654752f)));
                    } else if (EPI == 5) {
                        atomicAdd(&outf[idx], v + bv);
                    } else {  // EPI 4, Q/K part: row-stride 2048
                        qk[(size_t)(gr0 + r) * 2048 + gc] = (bf16)v;
                    }
                }
            }
        }
    }
}
#undef STAGE

// ---------------------------------------------------------------------------
// Causal flash attention v3. Fixed-shift softmax (shift=12; exact softmax).
// Round-7 delta (T14 async-STAGE split, +17% on attn per m214v27):
// K/V for tile t+1 are loaded into REGISTERS right after this tile's
// barrier; the QK+softmax+PV compute phase hides the global-load latency.
// The LDS write happens at the top of t+1 (region is free: closing
// __syncthreads of t guarantees all reads of Ks/Vs completed).
// ---------------------------------------------------------------------------
__global__ __launch_bounds__(256, 4) void flash_attn(const bf16* __restrict__ qk,
                                                     const bf16* __restrict__ vt,
                                                     bf16* __restrict__ attn) {
    __shared__ alignas(16) bf16 Ks[64 * 72];
    __shared__ alignas(16) bf16 Vs[64 * 72];
    __shared__ alignas(16) bf16 Ps[4][16 * 72];
    const int tid = threadIdx.x;
    const int wave = tid >> 6, lane = tid & 63;
    const int l16 = lane & 15, quad = lane >> 4;
    const int bh = blockIdx.x;
    const int qt = 31 - blockIdx.y;
    const int b = bh >> 4, h = bh & 15;
    const int q0w = qt * 64 + wave * 16;
    const bf16* qkb = qk + (size_t)b * 2048 * 2048;
    const bf16* vtb = vt + (size_t)bh * 64 * 2048;

    bf16x8 qf[2];
#pragma unroll
    for (int c = 0; c < 2; c++) {
        bf16x8 v = *(const bf16x8*)(qkb + (size_t)(q0w + l16) * 2048 +
                                    h * 64 + c * 32 + quad * 8);
#pragma unroll
        for (int e = 0; e < 8; e++) v[e] = (bf16)((float)v[e] * 0.125f);
        qf[c] = v;
    }

    float lsum[4] = {0.0f, 0.0f, 0.0f, 0.0f};
    f32x4 o[4] = {};

    const int ntiles = qt + 1;
    const int sr = tid >> 3, sch = tid & 7;   // staging task: rows sr, sr+32

    // prologue: tile 0 K/V -> registers
    uint4 kreg[2], vreg[2];
#pragma unroll
    for (int i = 0; i < 2; i++) {
        const int r = i * 32 + sr;
        kreg[i] = *(const uint4*)(qkb + (size_t)r * 2048 + 1024 + h * 64 + sch * 8);
        vreg[i] = *(const uint4*)(vtb + (size_t)r * 2048 + sch * 8);
    }

    for (int t = 0; t < ntiles; t++) {
        const int k0 = t * 64;
        // write staged registers to LDS (region free per last barrier)
#pragma unroll
        for (int i = 0; i < 2; i++) {
            const int r = i * 32 + sr;
            *(uint4*)(&Ks[r * 72 + sch * 8]) = kreg[i];
            *(uint4*)(&Vs[r * 72 + sch * 8]) = vreg[i];
        }
        __syncthreads();
        // issue next tile's loads now; latency hides under QK/softmax/PV
        if (t + 1 < ntiles) {
            const int k1 = k0 + 64;
#pragma unroll
            for (int i = 0; i < 2; i++) {
                const int r = i * 32 + sr;
                kreg[i] = *(const uint4*)(qkb + (size_t)(k1 + r) * 2048 +
                                          1024 + h * 64 + sch * 8);
                vreg[i] = *(const uint4*)(vtb + (size_t)r * 2048 + k1 + sch * 8);
            }
        }
        f32x4 s[4];
        __builtin_amdgcn_s_setprio(1);
#pragma unroll
        for (int kt = 0; kt < 4; kt++) {
            const bf16x8 k0f = *(const bf16x8*)(&Ks[(kt * 16 + l16) * 72 + quad * 8]);
            const bf16x8 k1f = *(const bf16x8*)(&Ks[(kt * 16 + l16) * 72 + 32 + quad * 8]);
            s[kt] = mfma16(qf[1], k1f, mfma16(qf[0], k0f, (f32x4){0, 0, 0, 0}));
        }
        __builtin_amdgcn_s_setprio(0);
        const bool need_mask = (t == ntiles - 1);
#pragma unroll
        for (int r = 0; r < 4; r++) {
            const int qrow = q0w + quad * 4 + r;
            float e0 = exp2f(fmaf(s[0][r], LOG2E, NSHIFT));
            float e1 = exp2f(fmaf(s[1][r], LOG2E, NSHIFT));
            float e2 = exp2f(fmaf(s[2][r], LOG2E, NSHIFT));
            float e3 = exp2f(fmaf(s[3][r], LOG2E, NSHIFT));
            if (need_mask) {
                if (k0 + l16 > qrow) e0 = 0.0f;
                if (k0 + 16 + l16 > qrow) e1 = 0.0f;
                if (k0 + 32 + l16 > qrow) e2 = 0.0f;
                if (k0 + 48 + l16 > qrow) e3 = 0.0f;
            }
            lsum[r] += (e0 + e1) + (e2 + e3);
            bf16* pp = &Ps[wave][(quad * 4 + r) * 72];
            pp[l16] = (bf16)e0;
            pp[16 + l16] = (bf16)e1;
            pp[32 + l16] = (bf16)e2;
            pp[48 + l16] = (bf16)e3;
        }
        // PV (Ps is per-wave private; lgkmcnt handles write->read in-wave)
        __builtin_amdgcn_s_setprio(1);
#pragma unroll
        for (int c = 0; c < 2; c++) {
            const bf16x8 pf = *(const bf16x8*)(&Ps[wave][l16 * 72 + c * 32 + quad * 8]);
#pragma unroll
            for (int dt = 0; dt < 4; dt++) {
                const bf16x8 vf =
                    *(const bf16x8*)(&Vs[(dt * 16 + l16) * 72 + c * 32 + quad * 8]);
                o[dt] = mfma16(pf, vf, o[dt]);
            }
        }
        __builtin_amdgcn_s_setprio(0);
        __syncthreads();
    }

    // epilogue: reduce l over the 16 lanes of each quad (bits 0-3)
#pragma unroll
    for (int r = 0; r < 4; r++) {
#pragma unroll
        for (int off = 1; off < 16; off <<= 1) lsum[r] += __shfl_xor(lsum[r], off);
        lsum[r] = 1.0f / fmaxf(lsum[r], 1e-30f);
    }
    bf16* ob = attn + (size_t)b * 2048 * 1024;
#pragma unroll
    for (int dt = 0; dt < 4; dt++)
#pragma unroll
        for (int r = 0; r < 4; r++) {
            const int q = q0w + quad * 4 + r;
            ob[(size_t)q * 1024 + h * 64 + dt * 16 + l16] = (bf16)(o[dt][r] * lsum[r]);
        }
}

// ---------------------------------------------------------------------------
extern "C" void kernel_launch(void* const* d_in, const int* in_sizes, int n_in,
                              void* d_out, int out_size, void* d_ws, size_t ws_size,
                              hipStream_t stream) {
    const float* x    = (const float*)d_in[0];
    const float* Wqkv = (const float*)d_in[2];
    const float* Wout = (const float*)d_in[3];
    const float* W1   = (const float*)d_in[4];
    const float* b1   = (const float*)d_in[5];
    const float* W2   = (const float*)d_in[6];
    const float* b2   = (const float*)d_in[7];
    const float* g1   = (const float*)d_in[8];
    const float* be1  = (const float*)d_in[9];
    const float* g2   = (const float*)d_in[10];
    const float* be2  = (const float*)d_in[11];

    char* ws = (char*)d_ws;
    bf16* Wb     = (bf16*)(ws);                 // all 4 weights, contiguous 24 MiB
    bf16* Wqkv_b = (bf16*)(ws);
    bf16* Wout_b = (bf16*)(ws + (6u << 20));
    bf16* W1_b   = (bf16*)(ws + (8u << 20));
    bf16* W2_b   = (bf16*)(ws + (16u << 20));
    bf16* h      = (bf16*)(ws + (24u << 20));
    bf16* qkbuf  = (bf16*)(ws + (32u << 20));
    bf16* vtbuf  = (bf16*)(ws + (48u << 20));
    bf16* attn   = (bf16*)(ws + (56u << 20));
    bf16* act    = (bf16*)(ws + (32u << 20));   // aliases qk/vt/attn post-attention
    float* x2    = (float*)d_out;               // residual stream lives in d_out

    // 0) all weights fp32 -> bf16 (one launch)
    cvt4_kernel<<<12288, 256, 0, stream>>>(Wqkv, Wout, W1, W2, Wb);

    // 1) h = LN1(x)
    ln_kernel<<<4096, 256, 0, stream>>>(x, h, g1, be1);
    // 2) qkv = h @ Wqkv^T -> qk rows + V^T   (ring-3)
    gemm_r3<4><<<dim3(32, 24), 256, 0, stream>>>(h, Wqkv_b, 3072, 1024, 1024,
                                                 nullptr, nullptr, nullptr, nullptr,
                                                 qkbuf, vtbuf);
    // 3) attn = causal_flash(qk, vt)   (T14 async-stage)
    flash_attn<<<dim3(32, 32), 256, 0, stream>>>(qkbuf, vtbuf, attn);
    // 4) x2 = attn @ Wout^T + x   (ring-3, fp32 into d_out)
    gemm_r3<1><<<dim3(32, 8), 256, 0, stream>>>(attn, Wout_b, 1024, 1024, 1024,
                                                nullptr, x2, nullptr, x, nullptr, nullptr);
    // 5) h = LN2(x2)
    ln_kernel<<<4096, 256, 0, stream>>>(x2, h, g2, be2);
    // 6) act = gelu(h @ W1^T + b1)   (ring-3)
    gemm_r3<2><<<dim3(32, 32), 256, 0, stream>>>(h, W1_b, 4096, 1024, 1024,
                                                 act, nullptr, b1, nullptr, nullptr, nullptr);
    // 7) out += act @ W2^T + b2   (ring-3, split-K=2, atomicAdd into x2)
    gemm_r3<5><<<dim3(32, 8, 2), 256, 0, stream>>>(act, W2_b, 1024, 2048, 4096,
                                                   nullptr, x2, b2, nullptr, nullptr, nullptr);
}

// Round 8
// 382.249 us; speedup vs baseline: 1.1107x; 1.1107x over previous
//
#include <hip/hip_runtime.h>
#include <hip/hip_bf16.h>
#include <math.h>

// B=2 S=2048 D=1024 H=16 DH=64 F=4096. ALL inputs/outputs fp32.
// Internals bf16 (MFMA) with fp32 accumulate; residual stream fp32 in d_out.
// Workspace (64 MiB):
//   [0,6)   Wqkv_b  [6,8) Wout_b  [8,16) W1_b  [16,24) W2_b  (contiguous: cvt4)
//   [24,32) h (LN outputs)
//   [32,48) qk [4096][2048] bf16   [48,56) vt [32][64][2048] bf16 V^T
//   [56,64) attn [4096][1024] bf16
//   [32,64) act [4096][4096] bf16 (FFN, aliases qk/vt/attn after attention)
//   x2 fp32 = d_out (out-proj writes; LN2 reads; FFN2 atomicAdds in place)
//
// Round 8: (1) flash_attn reverted to r5-exact (r7's T14 reg-staging spilled:
// VGPR 44, 93 MB scratch writes, 100.6us). (2) ring-3 GEMM gains an
// XCD-contiguous + GROUP_M=8 block remap (isolated this time — r4's test was
// confounded by a launch-bounds spill): consumers read tensors written by
// OTHER kernels on other XCDs -> L2-cold reads at L3 latency; banded remap
// keeps each XCD's resident working set small & reused -> L2 hits -> ring-3's
// 2-iteration prefetch window suffices.

typedef __bf16 bf16;
typedef __bf16 bf16x4 __attribute__((ext_vector_type(4)));
typedef __bf16 bf16x8 __attribute__((ext_vector_type(8)));
typedef float f32x4 __attribute__((ext_vector_type(4)));

#define LOG2E 1.4426950408889634f
#define NSHIFT -17.312340489f   // -12 * log2(e): fixed softmax shift of 12

__device__ __forceinline__ f32x4 mfma16(bf16x8 a, bf16x8 b, f32x4 c) {
    return __builtin_amdgcn_mfma_f32_16x16x32_bf16(a, b, c, 0, 0, 0);
}
// async global->LDS, 16B per lane; LDS dest = wave-uniform base + lane*16
__device__ __forceinline__ void load16_lds(const bf16* g, bf16* l) {
    __builtin_amdgcn_global_load_lds(
        (__attribute__((address_space(1))) void*)g,
        (__attribute__((address_space(3))) void*)l, 16, 0, 0);
}

// ---------------------------------------------------------------------------
// All four weight tensors fp32 -> bf16 in one launch; dst regions contiguous.
// ---------------------------------------------------------------------------
__global__ __launch_bounds__(256) void cvt4_kernel(const float* __restrict__ s0,
                                                   const float* __restrict__ s1,
                                                   const float* __restrict__ s2,
                                                   const float* __restrict__ s3,
                                                   bf16* __restrict__ dst) {
    const int blk = blockIdx.x;
    const float* s;
    int base;
    if (blk < 3072)      { s = s0; base = blk * 1024; }
    else if (blk < 4096) { s = s1; base = (blk - 3072) * 1024; }
    else if (blk < 8192) { s = s2; base = (blk - 4096) * 1024; }
    else                 { s = s3; base = (blk - 8192) * 1024; }
    const int t4 = threadIdx.x * 4;
    const float4 f = *(const float4*)(s + base + t4);
    bf16x4 o;
    o[0] = (bf16)f.x; o[1] = (bf16)f.y; o[2] = (bf16)f.z; o[3] = (bf16)f.w;
    *(bf16x4*)(dst + (size_t)blk * 1024 + t4) = o;
}

// ---------------------------------------------------------------------------
// LayerNorm row of 1024: fp32 in -> bf16 out. (x-mean)/(sqrt(var)+eps)
// ---------------------------------------------------------------------------
__global__ __launch_bounds__(256) void ln_kernel(const float* __restrict__ xin,
                                                 bf16* __restrict__ out,
                                                 const float* __restrict__ gamma,
                                                 const float* __restrict__ beta) {
    const int row = blockIdx.x;
    const int tid = threadIdx.x;
    const float4 f = *(const float4*)(xin + (size_t)row * 1024 + tid * 4);
    float v[4] = {f.x, f.y, f.z, f.w};
    float s = v[0] + v[1] + v[2] + v[3];
    float s2 = v[0] * v[0] + v[1] * v[1] + v[2] * v[2] + v[3] * v[3];
#pragma unroll
    for (int off = 1; off < 64; off <<= 1) {
        s += __shfl_xor(s, off);
        s2 += __shfl_xor(s2, off);
    }
    __shared__ float red[8];
    const int wave = tid >> 6, lane = tid & 63;
    if (lane == 0) { red[wave] = s; red[4 + wave] = s2; }
    __syncthreads();
    s = red[0] + red[1] + red[2] + red[3];
    s2 = red[4] + red[5] + red[6] + red[7];
    const float mean = s * (1.0f / 1024.0f);
    float var = s2 * (1.0f / 1024.0f) - mean * mean;
    var = fmaxf(var, 0.0f);
    const float rstd = 1.0f / (sqrtf(var) + 1e-6f);
    const int c = tid * 4;
    const float4 g = *(const float4*)(gamma + c);
    const float4 b = *(const float4*)(beta + c);
    bf16x4 o;
    o[0] = (bf16)((v[0] - mean) * rstd * g.x + b.x);
    o[1] = (bf16)((v[1] - mean) * rstd * g.y + b.y);
    o[2] = (bf16)((v[2] - mean) * rstd * g.z + b.z);
    o[3] = (bf16)((v[3] - mean) * rstd * g.w + b.w);
    *(bf16x4*)(out + (size_t)row * 1024 + c) = o;
}

// ---------------------------------------------------------------------------
// gemm_r3: RING-3 LDS 128x128/BK=32 (r2/r5-verified body; FFN1 75us,
// MfmaUtil 17.5, 0 bank conflicts). Single GEMM engine for all four GEMMs.
//   iter t: issue STAGE(t+2) -> ds_read/MFMA tile t -> s_waitcnt vmcnt(4)
//   -> raw s_barrier. Never vmcnt(0) in the main loop (T4).
// Round-8 delta: 1-D grid + bijective XCD-chunk (bid%8 -> contiguous range)
// + GROUP_M=8 banding. Requires grid%8==0 and nbm%8==0 (true for all four
// launches). Same remap passed correctness in r4; this time WITHOUT the
// (256,5) bound that spilled there.
// XOR bank swizzle: staging (row, slot c) fetches global chunk
// c ^ ((row>>1)&3); readers fetch phys chunk quad ^ ((row>>1)&3) -> 0
// conflicts (verified).
// EPI: 1=+fp32 res -> fp32   2=+bias,GELU -> bf16
//      4=qkv split store (qk + vt)   5=atomicAdd fp32 (+bias if kz==0)
// ---------------------------------------------------------------------------
#define STAGE(tt, bi)                                              \
    do {                                                           \
        const int _k0 = (tt) << 5;                                 \
        load16_lds(Ap + _k0, &As[bi][tid * 8]);                    \
        load16_lds(Bp + _k0, &Bs[bi][tid * 8]);                    \
        load16_lds(Ap + rstep + _k0, &As[bi][tid * 8 + 2048]);     \
        load16_lds(Bp + rstep + _k0, &Bs[bi][tid * 8 + 2048]);     \
    } while (0)

template <int EPI>
__global__ __launch_bounds__(256, 3) void gemm_r3(const bf16* __restrict__ A,
                                                  const bf16* __restrict__ B,
                                                  int nbm, int nbn,
                                                  int N, int K, int ldk,
                                                  bf16* __restrict__ outb,
                                                  float* __restrict__ outf,
                                                  const float* __restrict__ bias,
                                                  const float* __restrict__ resf,
                                                  bf16* __restrict__ qk,
                                                  bf16* __restrict__ vt) {
    __shared__ alignas(16) bf16 As[3][128 * 32];
    __shared__ alignas(16) bf16 Bs[3][128 * 32];
    const int tid = threadIdx.x;

    // --- bijective block remap: XCD-chunk then GROUP_M=8 banding ---
    int bid = blockIdx.x;
    const int nwg = nbm * nbn;
    bid = (bid & 7) * (nwg >> 3) + (bid >> 3);   // each XCD: contiguous range
    const int bandsz = nbn << 3;                 // 8 bm-rows x all bn
    const int band = bid / bandsz;
    const int rem = bid - band * bandsz;
    const int bm = (band << 3) + (rem & 7);
    const int bn = rem >> 3;

    const int wave = tid >> 6, lane = tid & 63;
    const int wm = (wave >> 1) * 64, wn = (wave & 1) * 64;
    const int l16 = lane & 15, quad = lane >> 4;

    f32x4 acc[4][4] = {};

    const size_t koff = (size_t)blockIdx.z * K;
    const int row0 = tid >> 2, ch0 = tid & 3;
    const int gch = ch0 ^ ((row0 >> 1) & 3);
    const bf16* Ap = A + (size_t)(bm * 128 + row0) * ldk + koff + gch * 8;
    const bf16* Bp = B + (size_t)(bn * 128 + row0) * ldk + koff + gch * 8;
    const size_t rstep = (size_t)64 * ldk;

    const int nt = K >> 5;                   // BK=32 K-steps (>= 3 always here)

    STAGE(0, 0);
    STAGE(1, 1);
    asm volatile("s_waitcnt vmcnt(4)" ::: "memory");
    __builtin_amdgcn_s_barrier();
    asm volatile("" ::: "memory");

    int i0 = 0, i1 = 1, i2 = 2;              // ring: i0=compute, i2=stage dest
    for (int t = 0; t < nt; ++t) {
        if (t + 2 < nt) STAGE(t + 2, i2);    // issue-early: 2-iter window

        bf16x8 af[4], bfr[4];
#pragma unroll
        for (int i = 0; i < 4; i++) {
            const int ra = wm + i * 16 + l16;
            af[i] = *(const bf16x8*)(&As[i0][ra * 32 + (quad ^ ((ra >> 1) & 3)) * 8]);
        }
#pragma unroll
        for (int j = 0; j < 4; j++) {
            const int rb = wn + j * 16 + l16;
            bfr[j] = *(const bf16x8*)(&Bs[i0][rb * 32 + (quad ^ ((rb >> 1) & 3)) * 8]);
        }
        __builtin_amdgcn_s_setprio(1);
#pragma unroll
        for (int i = 0; i < 4; i++)
#pragma unroll
            for (int j = 0; j < 4; j++) acc[i][j] = mfma16(af[i], bfr[j], acc[i][j]);
        __builtin_amdgcn_s_setprio(0);

        if (t + 2 < nt) {
            asm volatile("s_waitcnt vmcnt(4)" ::: "memory");
        } else if (t + 1 < nt) {
            asm volatile("s_waitcnt vmcnt(0)" ::: "memory");
        }
        if (t + 1 < nt) {
            __builtin_amdgcn_s_barrier();
            asm volatile("" ::: "memory");
        }
        const int tmp = i0; i0 = i1; i1 = i2; i2 = tmp;
    }

#pragma unroll
    for (int i = 0; i < 4; i++) {
#pragma unroll
        for (int j = 0; j < 4; j++) {
            const int gr0 = bm * 128 + wm + i * 16 + quad * 4;
            const int gc = bn * 128 + wn + j * 16 + l16;
            float bv = 0.0f;
            if (EPI == 2) bv = bias[gc];
            if (EPI == 5 && bias && blockIdx.z == 0) bv = bias[gc];
            if (EPI == 4 && gc >= 2048) {
                // V part -> vt[b][h][d][s], packed over 4 consecutive s
                const int n = gc - 2048;
                const int hh = n >> 6, dd = n & 63;
                const int bb = gr0 >> 11, ss = gr0 & 2047;
                bf16x4 pk;
#pragma unroll
                for (int r = 0; r < 4; r++) pk[r] = (bf16)acc[i][j][r];
                *(bf16x4*)(vt + ((size_t)((bb * 16 + hh) * 64 + dd)) * 2048 + ss) = pk;
            } else {
#pragma unroll
                for (int r = 0; r < 4; r++) {
                    const float v = acc[i][j][r];
                    const size_t idx = (size_t)(gr0 + r) * N + gc;
                    if (EPI == 1) {
                        outf[idx] = v + resf[idx];
                    } else if (EPI == 2) {
                        const float t = v + bv;
                        outb[idx] = (bf16)(0.5f * t * (1.0f + erff(t * 0.70710678118654752f)));
                    } else if (EPI == 5) {
                        atomicAdd(&outf[idx], v + bv);
                    } else {  // EPI 4, Q/K part: row-stride 2048
                        qk[(size_t)(gr0 + r) * 2048 + gc] = (bf16)v;
                    }
                }
            }
        }
    }
}
#undef STAGE

// ---------------------------------------------------------------------------
// Causal flash attention v3 — r5-exact body (verified ~55us; r7's reg-staged
// variant spilled and is reverted). Fixed-shift softmax (shift=12).
// ---------------------------------------------------------------------------
__global__ __launch_bounds__(256, 4) void flash_attn(const bf16* __restrict__ qk,
                                                     const bf16* __restrict__ vt,
                                                     bf16* __restrict__ attn) {
    __shared__ alignas(16) bf16 Ks[64 * 72];
    __shared__ alignas(16) bf16 Vs[64 * 72];
    __shared__ alignas(16) bf16 Ps[4][16 * 72];
    const int tid = threadIdx.x;
    const int wave = tid >> 6, lane = tid & 63;
    const int l16 = lane & 15, quad = lane >> 4;
    const int bh = blockIdx.x;
    const int qt = 31 - blockIdx.y;
    const int b = bh >> 4, h = bh & 15;
    const int q0w = qt * 64 + wave * 16;
    const bf16* qkb = qk + (size_t)b * 2048 * 2048;
    const bf16* vtb = vt + (size_t)bh * 64 * 2048;

    bf16x8 qf[2];
#pragma unroll
    for (int c = 0; c < 2; c++) {
        bf16x8 v = *(const bf16x8*)(qkb + (size_t)(q0w + l16) * 2048 +
                                    h * 64 + c * 32 + quad * 8);
#pragma unroll
        for (int e = 0; e < 8; e++) v[e] = (bf16)((float)v[e] * 0.125f);
        qf[c] = v;
    }

    float lsum[4] = {0.0f, 0.0f, 0.0f, 0.0f};
    f32x4 o[4] = {};

    const int ntiles = qt + 1;
    for (int t = 0; t < ntiles; t++) {
        const int k0 = t * 64;
#pragma unroll
        for (int i = 0; i < 2; i++) {
            const int r = i * 32 + (tid >> 3), ch = tid & 7;
            *(uint4*)(&Ks[r * 72 + ch * 8]) =
                *(const uint4*)(qkb + (size_t)(k0 + r) * 2048 + 1024 + h * 64 + ch * 8);
            *(uint4*)(&Vs[r * 72 + ch * 8]) =
                *(const uint4*)(vtb + (size_t)r * 2048 + k0 + ch * 8);
        }
        __syncthreads();
        f32x4 s[4];
        __builtin_amdgcn_s_setprio(1);
#pragma unroll
        for (int kt = 0; kt < 4; kt++) {
            const bf16x8 k0f = *(const bf16x8*)(&Ks[(kt * 16 + l16) * 72 + quad * 8]);
            const bf16x8 k1f = *(const bf16x8*)(&Ks[(kt * 16 + l16) * 72 + 32 + quad * 8]);
            s[kt] = mfma16(qf[1], k1f, mfma16(qf[0], k0f, (f32x4){0, 0, 0, 0}));
        }
        __builtin_amdgcn_s_setprio(0);
        const bool need_mask = (t == ntiles - 1);
#pragma unroll
        for (int r = 0; r < 4; r++) {
            const int qrow = q0w + quad * 4 + r;
            float e0 = exp2f(fmaf(s[0][r], LOG2E, NSHIFT));
            float e1 = exp2f(fmaf(s[1][r], LOG2E, NSHIFT));
            float e2 = exp2f(fmaf(s[2][r], LOG2E, NSHIFT));
            float e3 = exp2f(fmaf(s[3][r], LOG2E, NSHIFT));
            if (need_mask) {
                if (k0 + l16 > qrow) e0 = 0.0f;
                if (k0 + 16 + l16 > qrow) e1 = 0.0f;
                if (k0 + 32 + l16 > qrow) e2 = 0.0f;
                if (k0 + 48 + l16 > qrow) e3 = 0.0f;
            }
            lsum[r] += (e0 + e1) + (e2 + e3);
            bf16* pp = &Ps[wave][(quad * 4 + r) * 72];
            pp[l16] = (bf16)e0;
            pp[16 + l16] = (bf16)e1;
            pp[32 + l16] = (bf16)e2;
            pp[48 + l16] = (bf16)e3;
        }
        // PV (Ps is per-wave private; lgkmcnt handles write->read in-wave)
        __builtin_amdgcn_s_setprio(1);
#pragma unroll
        for (int c = 0; c < 2; c++) {
            const bf16x8 pf = *(const bf16x8*)(&Ps[wave][l16 * 72 + c * 32 + quad * 8]);
#pragma unroll
            for (int dt = 0; dt < 4; dt++) {
                const bf16x8 vf =
                    *(const bf16x8*)(&Vs[(dt * 16 + l16) * 72 + c * 32 + quad * 8]);
                o[dt] = mfma16(pf, vf, o[dt]);
            }
        }
        __builtin_amdgcn_s_setprio(0);
        __syncthreads();
    }

    // epilogue: reduce l over the 16 lanes of each quad (bits 0-3)
#pragma unroll
    for (int r = 0; r < 4; r++) {
#pragma unroll
        for (int off = 1; off < 16; off <<= 1) lsum[r] += __shfl_xor(lsum[r], off);
        lsum[r] = 1.0f / fmaxf(lsum[r], 1e-30f);
    }
    bf16* ob = attn + (size_t)b * 2048 * 1024;
#pragma unroll
    for (int dt = 0; dt < 4; dt++)
#pragma unroll
        for (int r = 0; r < 4; r++) {
            const int q = q0w + quad * 4 + r;
            ob[(size_t)q * 1024 + h * 64 + dt * 16 + l16] = (bf16)(o[dt][r] * lsum[r]);
        }
}

// ---------------------------------------------------------------------------
extern "C" void kernel_launch(void* const* d_in, const int* in_sizes, int n_in,
                              void* d_out, int out_size, void* d_ws, size_t ws_size,
                              hipStream_t stream) {
    const float* x    = (const float*)d_in[0];
    const float* Wqkv = (const float*)d_in[2];
    const float* Wout = (const float*)d_in[3];
    const float* W1   = (const float*)d_in[4];
    const float* b1   = (const float*)d_in[5];
    const float* W2   = (const float*)d_in[6];
    const float* b2   = (const float*)d_in[7];
    const float* g1   = (const float*)d_in[8];
    const float* be1  = (const float*)d_in[9];
    const float* g2   = (const float*)d_in[10];
    const float* be2  = (const float*)d_in[11];

    char* ws = (char*)d_ws;
    bf16* Wb     = (bf16*)(ws);                 // all 4 weights, contiguous 24 MiB
    bf16* Wqkv_b = (bf16*)(ws);
    bf16* Wout_b = (bf16*)(ws + (6u << 20));
    bf16* W1_b   = (bf16*)(ws + (8u << 20));
    bf16* W2_b   = (bf16*)(ws + (16u << 20));
    bf16* h      = (bf16*)(ws + (24u << 20));
    bf16* qkbuf  = (bf16*)(ws + (32u << 20));
    bf16* vtbuf  = (bf16*)(ws + (48u << 20));
    bf16* attn   = (bf16*)(ws + (56u << 20));
    bf16* act    = (bf16*)(ws + (32u << 20));   // aliases qk/vt/attn post-attention
    float* x2    = (float*)d_out;               // residual stream lives in d_out

    // 0) all weights fp32 -> bf16 (one launch)
    cvt4_kernel<<<12288, 256, 0, stream>>>(Wqkv, Wout, W1, W2, Wb);

    // 1) h = LN1(x)
    ln_kernel<<<4096, 256, 0, stream>>>(x, h, g1, be1);
    // 2) qkv = h @ Wqkv^T -> qk rows + V^T   (ring-3 + remap, 768 blocks)
    gemm_r3<4><<<768, 256, 0, stream>>>(h, Wqkv_b, 32, 24, 3072, 1024, 1024,
                                        nullptr, nullptr, nullptr, nullptr,
                                        qkbuf, vtbuf);
    // 3) attn = causal_flash(qk, vt)   (r5-exact)
    flash_attn<<<dim3(32, 32), 256, 0, stream>>>(qkbuf, vtbuf, attn);
    // 4) x2 = attn @ Wout^T + x   (ring-3 + remap, 256 blocks)
    gemm_r3<1><<<256, 256, 0, stream>>>(attn, Wout_b, 32, 8, 1024, 1024, 1024,
                                        nullptr, x2, nullptr, x, nullptr, nullptr);
    // 5) h = LN2(x2)
    ln_kernel<<<4096, 256, 0, stream>>>(x2, h, g2, be2);
    // 6) act = gelu(h @ W1^T + b1)   (ring-3 + remap, 1024 blocks)
    gemm_r3<2><<<1024, 256, 0, stream>>>(h, W1_b, 32, 32, 4096, 1024, 1024,
                                         act, nullptr, b1, nullptr, nullptr, nullptr);
    // 7) out += act @ W2^T + b2   (ring-3 + remap, split-K=2, atomicAdd)
    gemm_r3<5><<<dim3(256, 1, 2), 256, 0, stream>>>(act, W2_b, 32, 8, 1024, 2048, 4096,
                                                    nullptr, x2, b2, nullptr, nullptr, nullptr);
}

// Round 9
// 365.712 us; speedup vs baseline: 1.1609x; 1.0452x over previous
//
#include <hip/hip_runtime.h>
#include <hip/hip_bf16.h>
#include <math.h>

// B=2 S=2048 D=1024 H=16 DH=64 F=4096. ALL inputs/outputs fp32.
// Internals bf16 (MFMA) with fp32 accumulate; residual stream fp32 in d_out.
// Workspace (64 MiB):
//   [0,6)   Wqkv_b  [6,8) Wout_b  [8,16) W1_b  [16,24) W2_b  (contiguous: cvt4)
//   [24,32) h (LN outputs)
//   [32,48) qk [4096][2048] bf16   [48,56) vt [32][64][2048] bf16 V^T
//   [56,64) attn [4096][1024] bf16
//   [32,64) act [4096][4096] bf16 (FFN, aliases qk/vt/attn after attention)
//   x2 fp32 = d_out (out-proj writes; LN2 reads; FFN2 atomicAdds in place)
//
// Round 9 = exact r5 composite (best verified, 378.3us) + ONE change:
// FFN1's GELU epilogue switches erff (~30+ VALU ops, the 31.9% VALUBusy
// signal in r8) to the exp2-sigmoid tanh-form (~8 ops, 1 v_exp_f32).
// r8's remap: FETCH 49->33MB but time flat -> not fetch-bound; reverted.

typedef __bf16 bf16;
typedef __bf16 bf16x4 __attribute__((ext_vector_type(4)));
typedef __bf16 bf16x8 __attribute__((ext_vector_type(8)));
typedef float f32x4 __attribute__((ext_vector_type(4)));

#define LOG2E 1.4426950408889634f
#define NSHIFT -17.312340489f   // -12 * log2(e): fixed softmax shift of 12

__device__ __forceinline__ f32x4 mfma16(bf16x8 a, bf16x8 b, f32x4 c) {
    return __builtin_amdgcn_mfma_f32_16x16x32_bf16(a, b, c, 0, 0, 0);
}
// async global->LDS, 16B per lane; LDS dest = wave-uniform base + lane*16
__device__ __forceinline__ void load16_lds(const bf16* g, bf16* l) {
    __builtin_amdgcn_global_load_lds(
        (__attribute__((address_space(1))) void*)g,
        (__attribute__((address_space(3))) void*)l, 16, 0, 0);
}
// gelu(t) ~= t * sigmoid(2*0.79788456*(t + 0.044715 t^3)); max abs err ~3e-3,
// an order below act's bf16 quantization step at these magnitudes.
__device__ __forceinline__ float gelu_fast(float t) {
    const float u = t * (0.7978845608f + 0.0356774081f * t * t);
    return t * __builtin_amdgcn_rcpf(1.0f + exp2f(-2.8853900818f * u));
}

// ---------------------------------------------------------------------------
// All four weight tensors fp32 -> bf16 in one launch; dst regions contiguous.
// ---------------------------------------------------------------------------
__global__ __launch_bounds__(256) void cvt4_kernel(const float* __restrict__ s0,
                                                   const float* __restrict__ s1,
                                                   const float* __restrict__ s2,
                                                   const float* __restrict__ s3,
                                                   bf16* __restrict__ dst) {
    const int blk = blockIdx.x;
    const float* s;
    int base;
    if (blk < 3072)      { s = s0; base = blk * 1024; }
    else if (blk < 4096) { s = s1; base = (blk - 3072) * 1024; }
    else if (blk < 8192) { s = s2; base = (blk - 4096) * 1024; }
    else                 { s = s3; base = (blk - 8192) * 1024; }
    const int t4 = threadIdx.x * 4;
    const float4 f = *(const float4*)(s + base + t4);
    bf16x4 o;
    o[0] = (bf16)f.x; o[1] = (bf16)f.y; o[2] = (bf16)f.z; o[3] = (bf16)f.w;
    *(bf16x4*)(dst + (size_t)blk * 1024 + t4) = o;
}

// ---------------------------------------------------------------------------
// LayerNorm row of 1024: fp32 in -> bf16 out. (x-mean)/(sqrt(var)+eps)
// ---------------------------------------------------------------------------
__global__ __launch_bounds__(256) void ln_kernel(const float* __restrict__ xin,
                                                 bf16* __restrict__ out,
                                                 const float* __restrict__ gamma,
                                                 const float* __restrict__ beta) {
    const int row = blockIdx.x;
    const int tid = threadIdx.x;
    const float4 f = *(const float4*)(xin + (size_t)row * 1024 + tid * 4);
    float v[4] = {f.x, f.y, f.z, f.w};
    float s = v[0] + v[1] + v[2] + v[3];
    float s2 = v[0] * v[0] + v[1] * v[1] + v[2] * v[2] + v[3] * v[3];
#pragma unroll
    for (int off = 1; off < 64; off <<= 1) {
        s += __shfl_xor(s, off);
        s2 += __shfl_xor(s2, off);
    }
    __shared__ float red[8];
    const int wave = tid >> 6, lane = tid & 63;
    if (lane == 0) { red[wave] = s; red[4 + wave] = s2; }
    __syncthreads();
    s = red[0] + red[1] + red[2] + red[3];
    s2 = red[4] + red[5] + red[6] + red[7];
    const float mean = s * (1.0f / 1024.0f);
    float var = s2 * (1.0f / 1024.0f) - mean * mean;
    var = fmaxf(var, 0.0f);
    const float rstd = 1.0f / (sqrtf(var) + 1e-6f);
    const int c = tid * 4;
    const float4 g = *(const float4*)(gamma + c);
    const float4 b = *(const float4*)(beta + c);
    bf16x4 o;
    o[0] = (bf16)((v[0] - mean) * rstd * g.x + b.x);
    o[1] = (bf16)((v[1] - mean) * rstd * g.y + b.y);
    o[2] = (bf16)((v[2] - mean) * rstd * g.z + b.z);
    o[3] = (bf16)((v[3] - mean) * rstd * g.w + b.w);
    *(bf16x4*)(out + (size_t)row * 1024 + c) = o;
}

// ---------------------------------------------------------------------------
// gemm_bt: round-0-verified 2-buffer 128x128/BK=32 body, (256,3).
// Used for out-proj (EPI 1) and FFN2 (EPI 5, split-K via blockIdx.z).
// XOR bank swizzle: staging (row, slot c) fetches global chunk
// c ^ ((row>>1)&3); readers fetch phys chunk quad ^ ((row>>1)&3) -> 0
// conflicts (verified).
// ---------------------------------------------------------------------------
template <int EPI>
__global__ __launch_bounds__(256, 3) void gemm_bt(const bf16* __restrict__ A,
                                                  const bf16* __restrict__ B,
                                                  int N, int K, int ldk,
                                                  bf16* __restrict__ outb,
                                                  float* __restrict__ outf,
                                                  const float* __restrict__ bias,
                                                  const float* __restrict__ resf,
                                                  bf16* __restrict__ qk,
                                                  bf16* __restrict__ vt) {
    __shared__ alignas(16) bf16 As[2][128 * 32];
    __shared__ alignas(16) bf16 Bs[2][128 * 32];
    const int tid = threadIdx.x;
    const int bm = blockIdx.x, bn = blockIdx.y;
    const int wave = tid >> 6, lane = tid & 63;
    const int wm = (wave >> 1) * 64, wn = (wave & 1) * 64;
    const int l16 = lane & 15, quad = lane >> 4;

    f32x4 acc[4][4] = {};

    const size_t koff = (size_t)blockIdx.z * K;
    const int row0 = tid >> 2, ch0 = tid & 3;
    const int gch = ch0 ^ ((row0 >> 1) & 3);  // source-permuted staging chunk
    const bf16* Ap = A + (size_t)(bm * 128 + row0) * ldk + koff + gch * 8;
    const bf16* Bp = B + (size_t)(bn * 128 + row0) * ldk + koff + gch * 8;
    const size_t rstep = (size_t)64 * ldk;   // row0+64: same swizzle

    // prologue: stage tile 0 into buffer 0
#pragma unroll
    for (int r = 0; r < 2; r++) {
        load16_lds(Ap + r * rstep, &As[0][tid * 8 + r * 2048]);
        load16_lds(Bp + r * rstep, &Bs[0][tid * 8 + r * 2048]);
    }
    __syncthreads();

    int buf = 0;
    for (int k0 = 0; k0 < K; k0 += 32, buf ^= 1) {
        if (k0 + 32 < K) {
#pragma unroll
            for (int r = 0; r < 2; r++) {
                load16_lds(Ap + r * rstep + k0 + 32, &As[buf ^ 1][tid * 8 + r * 2048]);
                load16_lds(Bp + r * rstep + k0 + 32, &Bs[buf ^ 1][tid * 8 + r * 2048]);
            }
        }
        bf16x8 af[4], bfr[4];
#pragma unroll
        for (int i = 0; i < 4; i++) {
            const int ra = wm + i * 16 + l16;
            af[i] = *(const bf16x8*)(&As[buf][ra * 32 + (quad ^ ((ra >> 1) & 3)) * 8]);
        }
#pragma unroll
        for (int j = 0; j < 4; j++) {
            const int rb = wn + j * 16 + l16;
            bfr[j] = *(const bf16x8*)(&Bs[buf][rb * 32 + (quad ^ ((rb >> 1) & 3)) * 8]);
        }
#pragma unroll
        for (int i = 0; i < 4; i++)
#pragma unroll
            for (int j = 0; j < 4; j++) acc[i][j] = mfma16(af[i], bfr[j], acc[i][j]);
        __syncthreads();  // drains prefetch (overlapped w/ ds_read+MFMA above)
    }

#pragma unroll
    for (int i = 0; i < 4; i++) {
#pragma unroll
        for (int j = 0; j < 4; j++) {
            const int gr0 = bm * 128 + wm + i * 16 + quad * 4;
            const int gc = bn * 128 + wn + j * 16 + l16;
            float bv = 0.0f;
            if (EPI == 5 && bias && blockIdx.z == 0) bv = bias[gc];
#pragma unroll
            for (int r = 0; r < 4; r++) {
                const float v = acc[i][j][r];
                const size_t idx = (size_t)(gr0 + r) * N + gc;
                if (EPI == 1) {
                    outf[idx] = v + resf[idx];
                } else if (EPI == 5) {
                    atomicAdd(&outf[idx], v + bv);
                } else {
                    outb[idx] = (bf16)v;
                }
            }
        }
    }
}

// ---------------------------------------------------------------------------
// gemm_r3: RING-3 LDS 128x128/BK=32 (r2/r5-verified body; FFN1 75us,
// MfmaUtil 17.5, 0 bank conflicts). Used for QKV (EPI 4) and FFN1 (EPI 2).
//   iter t: issue STAGE(t+2) -> ds_read/MFMA tile t -> s_waitcnt vmcnt(4)
//   -> raw s_barrier. Never vmcnt(0) in the main loop (T4).
// Round-9 delta: EPI 2 uses gelu_fast (exp2-sigmoid) instead of erff.
// ---------------------------------------------------------------------------
#define STAGE(tt, bi)                                              \
    do {                                                           \
        const int _k0 = (tt) << 5;                                 \
        load16_lds(Ap + _k0, &As[bi][tid * 8]);                    \
        load16_lds(Bp + _k0, &Bs[bi][tid * 8]);                    \
        load16_lds(Ap + rstep + _k0, &As[bi][tid * 8 + 2048]);     \
        load16_lds(Bp + rstep + _k0, &Bs[bi][tid * 8 + 2048]);     \
    } while (0)

template <int EPI>
__global__ __launch_bounds__(256, 3) void gemm_r3(const bf16* __restrict__ A,
                                                  const bf16* __restrict__ B,
                                                  int N, int K, int ldk,
                                                  bf16* __restrict__ outb,
                                                  float* __restrict__ outf,
                                                  const float* __restrict__ bias,
                                                  const float* __restrict__ resf,
                                                  bf16* __restrict__ qk,
                                                  bf16* __restrict__ vt) {
    __shared__ alignas(16) bf16 As[3][128 * 32];
    __shared__ alignas(16) bf16 Bs[3][128 * 32];
    const int tid = threadIdx.x;
    const int bm = blockIdx.x, bn = blockIdx.y;
    const int wave = tid >> 6, lane = tid & 63;
    const int wm = (wave >> 1) * 64, wn = (wave & 1) * 64;
    const int l16 = lane & 15, quad = lane >> 4;

    f32x4 acc[4][4] = {};

    const size_t koff = (size_t)blockIdx.z * K;
    const int row0 = tid >> 2, ch0 = tid & 3;
    const int gch = ch0 ^ ((row0 >> 1) & 3);
    const bf16* Ap = A + (size_t)(bm * 128 + row0) * ldk + koff + gch * 8;
    const bf16* Bp = B + (size_t)(bn * 128 + row0) * ldk + koff + gch * 8;
    const size_t rstep = (size_t)64 * ldk;

    const int nt = K >> 5;                   // BK=32 K-steps (>= 3 always here)

    STAGE(0, 0);
    STAGE(1, 1);
    asm volatile("s_waitcnt vmcnt(4)" ::: "memory");
    __builtin_amdgcn_s_barrier();
    asm volatile("" ::: "memory");

    int i0 = 0, i1 = 1, i2 = 2;              // ring: i0=compute, i2=stage dest
    for (int t = 0; t < nt; ++t) {
        if (t + 2 < nt) STAGE(t + 2, i2);    // issue-early: 2-iter window

        bf16x8 af[4], bfr[4];
#pragma unroll
        for (int i = 0; i < 4; i++) {
            const int ra = wm + i * 16 + l16;
            af[i] = *(const bf16x8*)(&As[i0][ra * 32 + (quad ^ ((ra >> 1) & 3)) * 8]);
        }
#pragma unroll
        for (int j = 0; j < 4; j++) {
            const int rb = wn + j * 16 + l16;
            bfr[j] = *(const bf16x8*)(&Bs[i0][rb * 32 + (quad ^ ((rb >> 1) & 3)) * 8]);
        }
        __builtin_amdgcn_s_setprio(1);
#pragma unroll
        for (int i = 0; i < 4; i++)
#pragma unroll
            for (int j = 0; j < 4; j++) acc[i][j] = mfma16(af[i], bfr[j], acc[i][j]);
        __builtin_amdgcn_s_setprio(0);

        if (t + 2 < nt) {
            asm volatile("s_waitcnt vmcnt(4)" ::: "memory");
        } else if (t + 1 < nt) {
            asm volatile("s_waitcnt vmcnt(0)" ::: "memory");
        }
        if (t + 1 < nt) {
            __builtin_amdgcn_s_barrier();
            asm volatile("" ::: "memory");
        }
        const int tmp = i0; i0 = i1; i1 = i2; i2 = tmp;
    }

#pragma unroll
    for (int i = 0; i < 4; i++) {
#pragma unroll
        for (int j = 0; j < 4; j++) {
            const int gr0 = bm * 128 + wm + i * 16 + quad * 4;
            const int gc = bn * 128 + wn + j * 16 + l16;
            float bv = 0.0f;
            if (EPI == 2) bv = bias[gc];
            if (EPI == 4 && gc >= 2048) {
                // V part -> vt[b][h][d][s], packed over 4 consecutive s
                const int n = gc - 2048;
                const int hh = n >> 6, dd = n & 63;
                const int bb = gr0 >> 11, ss = gr0 & 2047;
                bf16x4 pk;
#pragma unroll
                for (int r = 0; r < 4; r++) pk[r] = (bf16)acc[i][j][r];
                *(bf16x4*)(vt + ((size_t)((bb * 16 + hh) * 64 + dd)) * 2048 + ss) = pk;
            } else {
#pragma unroll
                for (int r = 0; r < 4; r++) {
                    const float v = acc[i][j][r];
                    if (EPI == 2) {
                        outb[(size_t)(gr0 + r) * N + gc] = (bf16)gelu_fast(v + bv);
                    } else {  // EPI 4, Q/K part: row-stride 2048
                        qk[(size_t)(gr0 + r) * 2048 + gc] = (bf16)v;
                    }
                }
            }
        }
    }
}
#undef STAGE

// ---------------------------------------------------------------------------
// Causal flash attention v3 — r5-exact body (verified ~55us).
// Fixed-shift softmax (shift=12; exact softmax, no online max/rescale).
// ---------------------------------------------------------------------------
__global__ __launch_bounds__(256, 4) void flash_attn(const bf16* __restrict__ qk,
                                                     const bf16* __restrict__ vt,
                                                     bf16* __restrict__ attn) {
    __shared__ alignas(16) bf16 Ks[64 * 72];
    __shared__ alignas(16) bf16 Vs[64 * 72];
    __shared__ alignas(16) bf16 Ps[4][16 * 72];
    const int tid = threadIdx.x;
    const int wave = tid >> 6, lane = tid & 63;
    const int l16 = lane & 15, quad = lane >> 4;
    const int bh = blockIdx.x;
    const int qt = 31 - blockIdx.y;
    const int b = bh >> 4, h = bh & 15;
    const int q0w = qt * 64 + wave * 16;
    const bf16* qkb = qk + (size_t)b * 2048 * 2048;
    const bf16* vtb = vt + (size_t)bh * 64 * 2048;

    bf16x8 qf[2];
#pragma unroll
    for (int c = 0; c < 2; c++) {
        bf16x8 v = *(const bf16x8*)(qkb + (size_t)(q0w + l16) * 2048 +
                                    h * 64 + c * 32 + quad * 8);
#pragma unroll
        for (int e = 0; e < 8; e++) v[e] = (bf16)((float)v[e] * 0.125f);
        qf[c] = v;
    }

    float lsum[4] = {0.0f, 0.0f, 0.0f, 0.0f};
    f32x4 o[4] = {};

    const int ntiles = qt + 1;
    for (int t = 0; t < ntiles; t++) {
        const int k0 = t * 64;
#pragma unroll
        for (int i = 0; i < 2; i++) {
            const int r = i * 32 + (tid >> 3), ch = tid & 7;
            *(uint4*)(&Ks[r * 72 + ch * 8]) =
                *(const uint4*)(qkb + (size_t)(k0 + r) * 2048 + 1024 + h * 64 + ch * 8);
            *(uint4*)(&Vs[r * 72 + ch * 8]) =
                *(const uint4*)(vtb + (size_t)r * 2048 + k0 + ch * 8);
        }
        __syncthreads();
        f32x4 s[4];
        __builtin_amdgcn_s_setprio(1);
#pragma unroll
        for (int kt = 0; kt < 4; kt++) {
            const bf16x8 k0f = *(const bf16x8*)(&Ks[(kt * 16 + l16) * 72 + quad * 8]);
            const bf16x8 k1f = *(const bf16x8*)(&Ks[(kt * 16 + l16) * 72 + 32 + quad * 8]);
            s[kt] = mfma16(qf[1], k1f, mfma16(qf[0], k0f, (f32x4){0, 0, 0, 0}));
        }
        __builtin_amdgcn_s_setprio(0);
        const bool need_mask = (t == ntiles - 1);
#pragma unroll
        for (int r = 0; r < 4; r++) {
            const int qrow = q0w + quad * 4 + r;
            float e0 = exp2f(fmaf(s[0][r], LOG2E, NSHIFT));
            float e1 = exp2f(fmaf(s[1][r], LOG2E, NSHIFT));
            float e2 = exp2f(fmaf(s[2][r], LOG2E, NSHIFT));
            float e3 = exp2f(fmaf(s[3][r], LOG2E, NSHIFT));
            if (need_mask) {
                if (k0 + l16 > qrow) e0 = 0.0f;
                if (k0 + 16 + l16 > qrow) e1 = 0.0f;
                if (k0 + 32 + l16 > qrow) e2 = 0.0f;
                if (k0 + 48 + l16 > qrow) e3 = 0.0f;
            }
            lsum[r] += (e0 + e1) + (e2 + e3);
            bf16* pp = &Ps[wave][(quad * 4 + r) * 72];
            pp[l16] = (bf16)e0;
            pp[16 + l16] = (bf16)e1;
            pp[32 + l16] = (bf16)e2;
            pp[48 + l16] = (bf16)e3;
        }
        // PV (Ps is per-wave private; lgkmcnt handles write->read in-wave)
        __builtin_amdgcn_s_setprio(1);
#pragma unroll
        for (int c = 0; c < 2; c++) {
            const bf16x8 pf = *(const bf16x8*)(&Ps[wave][l16 * 72 + c * 32 + quad * 8]);
#pragma unroll
            for (int dt = 0; dt < 4; dt++) {
                const bf16x8 vf =
                    *(const bf16x8*)(&Vs[(dt * 16 + l16) * 72 + c * 32 + quad * 8]);
                o[dt] = mfma16(pf, vf, o[dt]);
            }
        }
        __builtin_amdgcn_s_setprio(0);
        __syncthreads();
    }

    // epilogue: reduce l over the 16 lanes of each quad (bits 0-3)
#pragma unroll
    for (int r = 0; r < 4; r++) {
#pragma unroll
        for (int off = 1; off < 16; off <<= 1) lsum[r] += __shfl_xor(lsum[r], off);
        lsum[r] = 1.0f / fmaxf(lsum[r], 1e-30f);
    }
    bf16* ob = attn + (size_t)b * 2048 * 1024;
#pragma unroll
    for (int dt = 0; dt < 4; dt++)
#pragma unroll
        for (int r = 0; r < 4; r++) {
            const int q = q0w + quad * 4 + r;
            ob[(size_t)q * 1024 + h * 64 + dt * 16 + l16] = (bf16)(o[dt][r] * lsum[r]);
        }
}

// ---------------------------------------------------------------------------
extern "C" void kernel_launch(void* const* d_in, const int* in_sizes, int n_in,
                              void* d_out, int out_size, void* d_ws, size_t ws_size,
                              hipStream_t stream) {
    const float* x    = (const float*)d_in[0];
    const float* Wqkv = (const float*)d_in[2];
    const float* Wout = (const float*)d_in[3];
    const float* W1   = (const float*)d_in[4];
    const float* b1   = (const float*)d_in[5];
    const float* W2   = (const float*)d_in[6];
    const float* b2   = (const float*)d_in[7];
    const float* g1   = (const float*)d_in[8];
    const float* be1  = (const float*)d_in[9];
    const float* g2   = (const float*)d_in[10];
    const float* be2  = (const float*)d_in[11];

    char* ws = (char*)d_ws;
    bf16* Wb     = (bf16*)(ws);                 // all 4 weights, contiguous 24 MiB
    bf16* Wqkv_b = (bf16*)(ws);
    bf16* Wout_b = (bf16*)(ws + (6u << 20));
    bf16* W1_b   = (bf16*)(ws + (8u << 20));
    bf16* W2_b   = (bf16*)(ws + (16u << 20));
    bf16* h      = (bf16*)(ws + (24u << 20));
    bf16* qkbuf  = (bf16*)(ws + (32u << 20));
    bf16* vtbuf  = (bf16*)(ws + (48u << 20));
    bf16* attn   = (bf16*)(ws + (56u << 20));
    bf16* act    = (bf16*)(ws + (32u << 20));   // aliases qk/vt/attn post-attention
    float* x2    = (float*)d_out;               // residual stream lives in d_out

    // 0) all weights fp32 -> bf16 (one launch)
    cvt4_kernel<<<12288, 256, 0, stream>>>(Wqkv, Wout, W1, W2, Wb);

    // 1) h = LN1(x)
    ln_kernel<<<4096, 256, 0, stream>>>(x, h, g1, be1);
    // 2) qkv = h @ Wqkv^T -> qk rows + V^T   (ring-3)
    gemm_r3<4><<<dim3(32, 24), 256, 0, stream>>>(h, Wqkv_b, 3072, 1024, 1024,
                                                 nullptr, nullptr, nullptr, nullptr,
                                                 qkbuf, vtbuf);
    // 3) attn = causal_flash(qk, vt)   (r5-exact)
    flash_attn<<<dim3(32, 32), 256, 0, stream>>>(qkbuf, vtbuf, attn);
    // 4) x2 = attn @ Wout^T + x   (fp32, into d_out; 2-buf r0 body)
    gemm_bt<1><<<dim3(32, 8), 256, 0, stream>>>(attn, Wout_b, 1024, 1024, 1024,
                                                nullptr, x2, nullptr, x, nullptr, nullptr);
    // 5) h = LN2(x2)
    ln_kernel<<<4096, 256, 0, stream>>>(x2, h, g2, be2);
    // 6) act = gelu_fast(h @ W1^T + b1)   (ring-3)
    gemm_r3<2><<<dim3(32, 32), 256, 0, stream>>>(h, W1_b, 4096, 1024, 1024,
                                                 act, nullptr, b1, nullptr, nullptr, nullptr);
    // 7) out += act @ W2^T + b2   (split-K=2, atomicAdd; 2-buf r0 body)
    gemm_bt<5><<<dim3(32, 8, 2), 256, 0, stream>>>(act, W2_b, 1024, 2048, 4096,
                                                   nullptr, x2, b2, nullptr, nullptr, nullptr);
}

// Round 10
// 363.234 us; speedup vs baseline: 1.1689x; 1.0068x over previous
//
#include <hip/hip_runtime.h>
#include <hip/hip_bf16.h>
#include <math.h>

// B=2 S=2048 D=1024 H=16 DH=64 F=4096. ALL inputs/outputs fp32.
// Internals bf16 (MFMA) with fp32 accumulate; residual stream fp32 in d_out.
// Workspace (64 MiB):
//   [0,6)   Wqkv_b  [6,8) Wout_b  [8,16) W1_b  [16,24) W2_b  (contiguous: cvt4)
//   [24,32) h (LN outputs)
//   [32,48) qk [4096][2048] bf16   [48,56) vt [32][64][2048] bf16 V^T
//   [56,64) attn [4096][1024] bf16
//   [32,64) act [4096][4096] bf16 (FFN, aliases qk/vt/attn after attention)
//   x2 fp32 = d_out (out-proj writes; LN2 reads; FFN2 atomicAdds in place)
//
// Round 10: single GEMM engine = ring-3 with EIGHT waves per block (same
// 128x128 tile, same 48 KiB ring LDS, same counted-vmcnt ledger with counts
// halved). r9 analysis: no pipe saturated (MFMA 17%, LDS 27%, L2 20%, HBM
// 14%) at 6.7 resident waves/CU -> latency-chain bound. 8 waves/block
// doubles per-SIMD wave count at zero LDS cost; per-wave acc 64->32 VGPR.

typedef __bf16 bf16;
typedef __bf16 bf16x4 __attribute__((ext_vector_type(4)));
typedef __bf16 bf16x8 __attribute__((ext_vector_type(8)));
typedef float f32x4 __attribute__((ext_vector_type(4)));

#define LOG2E 1.4426950408889634f
#define NSHIFT -17.312340489f   // -12 * log2(e): fixed softmax shift of 12

__device__ __forceinline__ f32x4 mfma16(bf16x8 a, bf16x8 b, f32x4 c) {
    return __builtin_amdgcn_mfma_f32_16x16x32_bf16(a, b, c, 0, 0, 0);
}
// async global->LDS, 16B per lane; LDS dest = wave-uniform base + lane*16
__device__ __forceinline__ void load16_lds(const bf16* g, bf16* l) {
    __builtin_amdgcn_global_load_lds(
        (__attribute__((address_space(1))) void*)g,
        (__attribute__((address_space(3))) void*)l, 16, 0, 0);
}
// gelu(t) ~= t * sigmoid(2*0.79788456*(t + 0.044715 t^3)); max abs err ~3e-3
__device__ __forceinline__ float gelu_fast(float t) {
    const float u = t * (0.7978845608f + 0.0356774081f * t * t);
    return t * __builtin_amdgcn_rcpf(1.0f + exp2f(-2.8853900818f * u));
}

// ---------------------------------------------------------------------------
// All four weight tensors fp32 -> bf16 in one launch; dst regions contiguous.
// ---------------------------------------------------------------------------
__global__ __launch_bounds__(256) void cvt4_kernel(const float* __restrict__ s0,
                                                   const float* __restrict__ s1,
                                                   const float* __restrict__ s2,
                                                   const float* __restrict__ s3,
                                                   bf16* __restrict__ dst) {
    const int blk = blockIdx.x;
    const float* s;
    int base;
    if (blk < 3072)      { s = s0; base = blk * 1024; }
    else if (blk < 4096) { s = s1; base = (blk - 3072) * 1024; }
    else if (blk < 8192) { s = s2; base = (blk - 4096) * 1024; }
    else                 { s = s3; base = (blk - 8192) * 1024; }
    const int t4 = threadIdx.x * 4;
    const float4 f = *(const float4*)(s + base + t4);
    bf16x4 o;
    o[0] = (bf16)f.x; o[1] = (bf16)f.y; o[2] = (bf16)f.z; o[3] = (bf16)f.w;
    *(bf16x4*)(dst + (size_t)blk * 1024 + t4) = o;
}

// ---------------------------------------------------------------------------
// LayerNorm row of 1024: fp32 in -> bf16 out. (x-mean)/(sqrt(var)+eps)
// ---------------------------------------------------------------------------
__global__ __launch_bounds__(256) void ln_kernel(const float* __restrict__ xin,
                                                 bf16* __restrict__ out,
                                                 const float* __restrict__ gamma,
                                                 const float* __restrict__ beta) {
    const int row = blockIdx.x;
    const int tid = threadIdx.x;
    const float4 f = *(const float4*)(xin + (size_t)row * 1024 + tid * 4);
    float v[4] = {f.x, f.y, f.z, f.w};
    float s = v[0] + v[1] + v[2] + v[3];
    float s2 = v[0] * v[0] + v[1] * v[1] + v[2] * v[2] + v[3] * v[3];
#pragma unroll
    for (int off = 1; off < 64; off <<= 1) {
        s += __shfl_xor(s, off);
        s2 += __shfl_xor(s2, off);
    }
    __shared__ float red[8];
    const int wave = tid >> 6, lane = tid & 63;
    if (lane == 0) { red[wave] = s; red[4 + wave] = s2; }
    __syncthreads();
    s = red[0] + red[1] + red[2] + red[3];
    s2 = red[4] + red[5] + red[6] + red[7];
    const float mean = s * (1.0f / 1024.0f);
    float var = s2 * (1.0f / 1024.0f) - mean * mean;
    var = fmaxf(var, 0.0f);
    const float rstd = 1.0f / (sqrtf(var) + 1e-6f);
    const int c = tid * 4;
    const float4 g = *(const float4*)(gamma + c);
    const float4 b = *(const float4*)(beta + c);
    bf16x4 o;
    o[0] = (bf16)((v[0] - mean) * rstd * g.x + b.x);
    o[1] = (bf16)((v[1] - mean) * rstd * g.y + b.y);
    o[2] = (bf16)((v[2] - mean) * rstd * g.z + b.z);
    o[3] = (bf16)((v[3] - mean) * rstd * g.w + b.w);
    *(bf16x4*)(out + (size_t)row * 1024 + c) = o;
}

// ---------------------------------------------------------------------------
// gemm_r3w8: RING-3 LDS 128x128/BK=32 with 8 waves (512 threads).
// Sync ledger identical to the verified ring-3, counts halved (each STAGE
// is 2 loads: 512 threads cover the full 8 KB A-tile + 8 KB B-tile in one
// sweep). iter t: issue STAGE(t+2) -> ds_read/MFMA tile t -> s_waitcnt
// vmcnt(2) (t+1's stage, issued a full iteration earlier, has retired;
// t+2's 2 loads stay in flight) -> raw s_barrier. Never vmcnt(0) in loop.
// Wave grid 2M x 4N: per wave 64x32 output, af[4]+bfr[2], acc[4][2]
// (32 VGPR acc vs 64 in the 4-wave version) -> 2x waves/SIMD for latency
// cover, A-tile read 2x, B-tile 2x through LDS (headroom: LDS was 27%).
// XOR bank swizzle unchanged: staging (row, slot c) fetches global chunk
// c ^ ((row>>1)&3); readers fetch phys chunk quad ^ ((row>>1)&3) -> 0
// conflicts (verified).
// EPI: 1=+fp32 res -> fp32   2=+bias, gelu_fast -> bf16
//      4=qkv split store (qk + vt)   5=atomicAdd fp32 (+bias if kz==0)
// ---------------------------------------------------------------------------
#define STAGE(tt, bi)                                              \
    do {                                                           \
        const int _k0 = (tt) << 5;                                 \
        load16_lds(Ap + _k0, &As[bi][tid * 8]);                    \
        load16_lds(Bp + _k0, &Bs[bi][tid * 8]);                    \
    } while (0)

template <int EPI>
__global__ __launch_bounds__(512, 4) void gemm_r3w8(const bf16* __restrict__ A,
                                                    const bf16* __restrict__ B,
                                                    int N, int K, int ldk,
                                                    bf16* __restrict__ outb,
                                                    float* __restrict__ outf,
                                                    const float* __restrict__ bias,
                                                    const float* __restrict__ resf,
                                                    bf16* __restrict__ qk,
                                                    bf16* __restrict__ vt) {
    __shared__ alignas(16) bf16 As[3][128 * 32];
    __shared__ alignas(16) bf16 Bs[3][128 * 32];
    const int tid = threadIdx.x;
    const int bm = blockIdx.x, bn = blockIdx.y;
    const int wave = tid >> 6, lane = tid & 63;
    const int wm = (wave >> 2) * 64, wn = (wave & 3) * 32;   // 2M x 4N
    const int l16 = lane & 15, quad = lane >> 4;

    f32x4 acc[4][2] = {};

    const size_t koff = (size_t)blockIdx.z * K;
    const int row0 = tid >> 2, ch0 = tid & 3;        // 512 thr: 128 rows x 4 ch
    const int gch = ch0 ^ ((row0 >> 1) & 3);         // source-permuted chunk
    const bf16* Ap = A + (size_t)(bm * 128 + row0) * ldk + koff + gch * 8;
    const bf16* Bp = B + (size_t)(bn * 128 + row0) * ldk + koff + gch * 8;

    const int nt = K >> 5;                   // BK=32 K-steps (>= 3 always here)

    STAGE(0, 0);
    STAGE(1, 1);
    asm volatile("s_waitcnt vmcnt(2)" ::: "memory");
    __builtin_amdgcn_s_barrier();
    asm volatile("" ::: "memory");

    int i0 = 0, i1 = 1, i2 = 2;              // ring: i0=compute, i2=stage dest
    for (int t = 0; t < nt; ++t) {
        if (t + 2 < nt) STAGE(t + 2, i2);    // issue-early: 2-iter window

        bf16x8 af[4], bfr[2];
#pragma unroll
        for (int i = 0; i < 4; i++) {
            const int ra = wm + i * 16 + l16;
            af[i] = *(const bf16x8*)(&As[i0][ra * 32 + (quad ^ ((ra >> 1) & 3)) * 8]);
        }
#pragma unroll
        for (int j = 0; j < 2; j++) {
            const int rb = wn + j * 16 + l16;
            bfr[j] = *(const bf16x8*)(&Bs[i0][rb * 32 + (quad ^ ((rb >> 1) & 3)) * 8]);
        }
        __builtin_amdgcn_s_setprio(1);
#pragma unroll
        for (int i = 0; i < 4; i++)
#pragma unroll
            for (int j = 0; j < 2; j++) acc[i][j] = mfma16(af[i], bfr[j], acc[i][j]);
        __builtin_amdgcn_s_setprio(0);

        if (t + 2 < nt) {
            asm volatile("s_waitcnt vmcnt(2)" ::: "memory");
        } else if (t + 1 < nt) {
            asm volatile("s_waitcnt vmcnt(0)" ::: "memory");
        }
        if (t + 1 < nt) {
            __builtin_amdgcn_s_barrier();
            asm volatile("" ::: "memory");
        }
        const int tmp = i0; i0 = i1; i1 = i2; i2 = tmp;
    }

#pragma unroll
    for (int i = 0; i < 4; i++) {
#pragma unroll
        for (int j = 0; j < 2; j++) {
            const int gr0 = bm * 128 + wm + i * 16 + quad * 4;
            const int gc = bn * 128 + wn + j * 16 + l16;
            float bv = 0.0f;
            if (EPI == 2) bv = bias[gc];
            if (EPI == 5 && bias && blockIdx.z == 0) bv = bias[gc];
            if (EPI == 4 && gc >= 2048) {
                // V part -> vt[b][h][d][s], packed over 4 consecutive s
                const int n = gc - 2048;
                const int hh = n >> 6, dd = n & 63;
                const int bb = gr0 >> 11, ss = gr0 & 2047;
                bf16x4 pk;
#pragma unroll
                for (int r = 0; r < 4; r++) pk[r] = (bf16)acc[i][j][r];
                *(bf16x4*)(vt + ((size_t)((bb * 16 + hh) * 64 + dd)) * 2048 + ss) = pk;
            } else {
#pragma unroll
                for (int r = 0; r < 4; r++) {
                    const float v = acc[i][j][r];
                    const size_t idx = (size_t)(gr0 + r) * N + gc;
                    if (EPI == 1) {
                        outf[idx] = v + resf[idx];
                    } else if (EPI == 2) {
                        outb[idx] = (bf16)gelu_fast(v + bv);
                    } else if (EPI == 5) {
                        atomicAdd(&outf[idx], v + bv);
                    } else {  // EPI 4, Q/K part: row-stride 2048
                        qk[(size_t)(gr0 + r) * 2048 + gc] = (bf16)v;
                    }
                }
            }
        }
    }
}
#undef STAGE

// ---------------------------------------------------------------------------
// Causal flash attention v3 — r5-exact body (verified ~55us).
// Fixed-shift softmax (shift=12; exact softmax, no online max/rescale).
// ---------------------------------------------------------------------------
__global__ __launch_bounds__(256, 4) void flash_attn(const bf16* __restrict__ qk,
                                                     const bf16* __restrict__ vt,
                                                     bf16* __restrict__ attn) {
    __shared__ alignas(16) bf16 Ks[64 * 72];
    __shared__ alignas(16) bf16 Vs[64 * 72];
    __shared__ alignas(16) bf16 Ps[4][16 * 72];
    const int tid = threadIdx.x;
    const int wave = tid >> 6, lane = tid & 63;
    const int l16 = lane & 15, quad = lane >> 4;
    const int bh = blockIdx.x;
    const int qt = 31 - blockIdx.y;
    const int b = bh >> 4, h = bh & 15;
    const int q0w = qt * 64 + wave * 16;
    const bf16* qkb = qk + (size_t)b * 2048 * 2048;
    const bf16* vtb = vt + (size_t)bh * 64 * 2048;

    bf16x8 qf[2];
#pragma unroll
    for (int c = 0; c < 2; c++) {
        bf16x8 v = *(const bf16x8*)(qkb + (size_t)(q0w + l16) * 2048 +
                                    h * 64 + c * 32 + quad * 8);
#pragma unroll
        for (int e = 0; e < 8; e++) v[e] = (bf16)((float)v[e] * 0.125f);
        qf[c] = v;
    }

    float lsum[4] = {0.0f, 0.0f, 0.0f, 0.0f};
    f32x4 o[4] = {};

    const int ntiles = qt + 1;
    for (int t = 0; t < ntiles; t++) {
        const int k0 = t * 64;
#pragma unroll
        for (int i = 0; i < 2; i++) {
            const int r = i * 32 + (tid >> 3), ch = tid & 7;
            *(uint4*)(&Ks[r * 72 + ch * 8]) =
                *(const uint4*)(qkb + (size_t)(k0 + r) * 2048 + 1024 + h * 64 + ch * 8);
            *(uint4*)(&Vs[r * 72 + ch * 8]) =
                *(const uint4*)(vtb + (size_t)r * 2048 + k0 + ch * 8);
        }
        __syncthreads();
        f32x4 s[4];
        __builtin_amdgcn_s_setprio(1);
#pragma unroll
        for (int kt = 0; kt < 4; kt++) {
            const bf16x8 k0f = *(const bf16x8*)(&Ks[(kt * 16 + l16) * 72 + quad * 8]);
            const bf16x8 k1f = *(const bf16x8*)(&Ks[(kt * 16 + l16) * 72 + 32 + quad * 8]);
            s[kt] = mfma16(qf[1], k1f, mfma16(qf[0], k0f, (f32x4){0, 0, 0, 0}));
        }
        __builtin_amdgcn_s_setprio(0);
        const bool need_mask = (t == ntiles - 1);
#pragma unroll
        for (int r = 0; r < 4; r++) {
            const int qrow = q0w + quad * 4 + r;
            float e0 = exp2f(fmaf(s[0][r], LOG2E, NSHIFT));
            float e1 = exp2f(fmaf(s[1][r], LOG2E, NSHIFT));
            float e2 = exp2f(fmaf(s[2][r], LOG2E, NSHIFT));
            float e3 = exp2f(fmaf(s[3][r], LOG2E, NSHIFT));
            if (need_mask) {
                if (k0 + l16 > qrow) e0 = 0.0f;
                if (k0 + 16 + l16 > qrow) e1 = 0.0f;
                if (k0 + 32 + l16 > qrow) e2 = 0.0f;
                if (k0 + 48 + l16 > qrow) e3 = 0.0f;
            }
            lsum[r] += (e0 + e1) + (e2 + e3);
            bf16* pp = &Ps[wave][(quad * 4 + r) * 72];
            pp[l16] = (bf16)e0;
            pp[16 + l16] = (bf16)e1;
            pp[32 + l16] = (bf16)e2;
            pp[48 + l16] = (bf16)e3;
        }
        // PV (Ps is per-wave private; lgkmcnt handles write->read in-wave)
        __builtin_amdgcn_s_setprio(1);
#pragma unroll
        for (int c = 0; c < 2; c++) {
            const bf16x8 pf = *(const bf16x8*)(&Ps[wave][l16 * 72 + c * 32 + quad * 8]);
#pragma unroll
            for (int dt = 0; dt < 4; dt++) {
                const bf16x8 vf =
                    *(const bf16x8*)(&Vs[(dt * 16 + l16) * 72 + c * 32 + quad * 8]);
                o[dt] = mfma16(pf, vf, o[dt]);
            }
        }
        __builtin_amdgcn_s_setprio(0);
        __syncthreads();
    }

    // epilogue: reduce l over the 16 lanes of each quad (bits 0-3)
#pragma unroll
    for (int r = 0; r < 4; r++) {
#pragma unroll
        for (int off = 1; off < 16; off <<= 1) lsum[r] += __shfl_xor(lsum[r], off);
        lsum[r] = 1.0f / fmaxf(lsum[r], 1e-30f);
    }
    bf16* ob = attn + (size_t)b * 2048 * 1024;
#pragma unroll
    for (int dt = 0; dt < 4; dt++)
#pragma unroll
        for (int r = 0; r < 4; r++) {
            const int q = q0w + quad * 4 + r;
            ob[(size_t)q * 1024 + h * 64 + dt * 16 + l16] = (bf16)(o[dt][r] * lsum[r]);
        }
}

// ---------------------------------------------------------------------------
extern "C" void kernel_launch(void* const* d_in, const int* in_sizes, int n_in,
                              void* d_out, int out_size, void* d_ws, size_t ws_size,
                              hipStream_t stream) {
    const float* x    = (const float*)d_in[0];
    const float* Wqkv = (const float*)d_in[2];
    const float* Wout = (const float*)d_in[3];
    const float* W1   = (const float*)d_in[4];
    const float* b1   = (const float*)d_in[5];
    const float* W2   = (const float*)d_in[6];
    const float* b2   = (const float*)d_in[7];
    const float* g1   = (const float*)d_in[8];
    const float* be1  = (const float*)d_in[9];
    const float* g2   = (const float*)d_in[10];
    const float* be2  = (const float*)d_in[11];

    char* ws = (char*)d_ws;
    bf16* Wb     = (bf16*)(ws);                 // all 4 weights, contiguous 24 MiB
    bf16* Wqkv_b = (bf16*)(ws);
    bf16* Wout_b = (bf16*)(ws + (6u << 20));
    bf16* W1_b   = (bf16*)(ws + (8u << 20));
    bf16* W2_b   = (bf16*)(ws + (16u << 20));
    bf16* h      = (bf16*)(ws + (24u << 20));
    bf16* qkbuf  = (bf16*)(ws + (32u << 20));
    bf16* vtbuf  = (bf16*)(ws + (48u << 20));
    bf16* attn   = (bf16*)(ws + (56u << 20));
    bf16* act    = (bf16*)(ws + (32u << 20));   // aliases qk/vt/attn post-attention
    float* x2    = (float*)d_out;               // residual stream lives in d_out

    // 0) all weights fp32 -> bf16 (one launch)
    cvt4_kernel<<<12288, 256, 0, stream>>>(Wqkv, Wout, W1, W2, Wb);

    // 1) h = LN1(x)
    ln_kernel<<<4096, 256, 0, stream>>>(x, h, g1, be1);
    // 2) qkv = h @ Wqkv^T -> qk rows + V^T   (ring-3, 8 waves)
    gemm_r3w8<4><<<dim3(32, 24), 512, 0, stream>>>(h, Wqkv_b, 3072, 1024, 1024,
                                                   nullptr, nullptr, nullptr, nullptr,
                                                   qkbuf, vtbuf);
    // 3) attn = causal_flash(qk, vt)   (r5-exact)
    flash_attn<<<dim3(32, 32), 256, 0, stream>>>(qkbuf, vtbuf, attn);
    // 4) x2 = attn @ Wout^T + x   (ring-3, 8 waves; fp32 into d_out)
    gemm_r3w8<1><<<dim3(32, 8), 512, 0, stream>>>(attn, Wout_b, 1024, 1024, 1024,
                                                  nullptr, x2, nullptr, x, nullptr, nullptr);
    // 5) h = LN2(x2)
    ln_kernel<<<4096, 256, 0, stream>>>(x2, h, g2, be2);
    // 6) act = gelu_fast(h @ W1^T + b1)   (ring-3, 8 waves)
    gemm_r3w8<2><<<dim3(32, 32), 512, 0, stream>>>(h, W1_b, 4096, 1024, 1024,
                                                   act, nullptr, b1, nullptr, nullptr, nullptr);
    // 7) out += act @ W2^T + b2   (ring-3, 8 waves, split-K=2, atomicAdd)
    gemm_r3w8<5><<<dim3(32, 8, 2), 512, 0, stream>>>(act, W2_b, 1024, 2048, 4096,
                                                     nullptr, x2, b2, nullptr, nullptr, nullptr);
}

// Round 11
// 359.639 us; speedup vs baseline: 1.1806x; 1.0100x over previous
//
#include <hip/hip_runtime.h>
#include <hip/hip_bf16.h>
#include <math.h>

// B=2 S=2048 D=1024 H=16 DH=64 F=4096. ALL inputs/outputs fp32.
// Internals bf16 (MFMA) with fp32 accumulate; residual stream fp32 in d_out.
// Workspace (64 MiB):
//   [0,6)   Wqkv_b  [6,8) Wout_b  [8,16) W1_b  [16,24) W2_b  (contiguous: cvt4)
//   [24,32) h (LN outputs)
//   [32,48) qk [4096][2048] bf16   [48,56) vt [32][64][2048] bf16 V^T
//   [56,64) attn [4096][1024] bf16
//   [32,64) act [4096][4096] bf16 (FFN, aliases qk/vt/attn after attention)
//   x2 fp32 = d_out (out-proj writes; LN2 reads; FFN2 atomicAdds in place)
//
// Round 11: (1) ring-4 (2-iteration prefetch window, vmcnt(4/2/0) ladder)
// for FFN2 + out-proj — the two GEMMs where 64 KiB LDS costs no residency
// (FFN2 grid-capped at 2/CU; out-proj 1/CU). r10 falsified TLP as the bound
// (occupancy 2x, time -4%); the remaining candidate is the cold-L2 load
// chain exceeding ring-3's one-iteration window. (2) cvt4+LN1 in one launch.

typedef __bf16 bf16;
typedef __bf16 bf16x4 __attribute__((ext_vector_type(4)));
typedef __bf16 bf16x8 __attribute__((ext_vector_type(8)));
typedef float f32x4 __attribute__((ext_vector_type(4)));

#define LOG2E 1.4426950408889634f
#define NSHIFT -17.312340489f   // -12 * log2(e): fixed softmax shift of 12

__device__ __forceinline__ f32x4 mfma16(bf16x8 a, bf16x8 b, f32x4 c) {
    return __builtin_amdgcn_mfma_f32_16x16x32_bf16(a, b, c, 0, 0, 0);
}
// async global->LDS, 16B per lane; LDS dest = wave-uniform base + lane*16
__device__ __forceinline__ void load16_lds(const bf16* g, bf16* l) {
    __builtin_amdgcn_global_load_lds(
        (__attribute__((address_space(1))) void*)g,
        (__attribute__((address_space(3))) void*)l, 16, 0, 0);
}
// gelu(t) ~= t * sigmoid(2*0.79788456*(t + 0.044715 t^3)); max abs err ~3e-3
__device__ __forceinline__ float gelu_fast(float t) {
    const float u = t * (0.7978845608f + 0.0356774081f * t * t);
    return t * __builtin_amdgcn_rcpf(1.0f + exp2f(-2.8853900818f * u));
}

// ---------------------------------------------------------------------------
// LN body (row of 1024, fp32 in -> bf16 out), shared by fused & standalone.
// ---------------------------------------------------------------------------
__device__ __forceinline__ void ln_row(const float* __restrict__ xin,
                                       bf16* __restrict__ out, int row, int tid,
                                       const float* __restrict__ gamma,
                                       const float* __restrict__ beta,
                                       float* red) {
    const float4 f = *(const float4*)(xin + (size_t)row * 1024 + tid * 4);
    float v[4] = {f.x, f.y, f.z, f.w};
    float s = v[0] + v[1] + v[2] + v[3];
    float s2 = v[0] * v[0] + v[1] * v[1] + v[2] * v[2] + v[3] * v[3];
#pragma unroll
    for (int off = 1; off < 64; off <<= 1) {
        s += __shfl_xor(s, off);
        s2 += __shfl_xor(s2, off);
    }
    const int wave = tid >> 6, lane = tid & 63;
    if (lane == 0) { red[wave] = s; red[4 + wave] = s2; }
    __syncthreads();
    s = red[0] + red[1] + red[2] + red[3];
    s2 = red[4] + red[5] + red[6] + red[7];
    const float mean = s * (1.0f / 1024.0f);
    float var = s2 * (1.0f / 1024.0f) - mean * mean;
    var = fmaxf(var, 0.0f);
    const float rstd = 1.0f / (sqrtf(var) + 1e-6f);
    const int c = tid * 4;
    const float4 g = *(const float4*)(gamma + c);
    const float4 b = *(const float4*)(beta + c);
    bf16x4 o;
    o[0] = (bf16)((v[0] - mean) * rstd * g.x + b.x);
    o[1] = (bf16)((v[1] - mean) * rstd * g.y + b.y);
    o[2] = (bf16)((v[2] - mean) * rstd * g.z + b.z);
    o[3] = (bf16)((v[3] - mean) * rstd * g.w + b.w);
    *(bf16x4*)(out + (size_t)row * 1024 + c) = o;
}

// ---------------------------------------------------------------------------
// Fused: blocks [0,12288) convert all 4 weight tensors fp32->bf16;
// blocks [12288,16384) run LN1 on rows 0..4095. Independent data.
// ---------------------------------------------------------------------------
__global__ __launch_bounds__(256) void cvt4_ln_kernel(const float* __restrict__ s0,
                                                      const float* __restrict__ s1,
                                                      const float* __restrict__ s2,
                                                      const float* __restrict__ s3,
                                                      bf16* __restrict__ dst,
                                                      const float* __restrict__ xin,
                                                      bf16* __restrict__ hout,
                                                      const float* __restrict__ gamma,
                                                      const float* __restrict__ beta) {
    __shared__ float red[8];
    const int blk = blockIdx.x;
    const int tid = threadIdx.x;
    if (blk >= 12288) {
        ln_row(xin, hout, blk - 12288, tid, gamma, beta, red);
        return;
    }
    const float* s;
    int base;
    if (blk < 3072)      { s = s0; base = blk * 1024; }
    else if (blk < 4096) { s = s1; base = (blk - 3072) * 1024; }
    else if (blk < 8192) { s = s2; base = (blk - 4096) * 1024; }
    else                 { s = s3; base = (blk - 8192) * 1024; }
    const int t4 = tid * 4;
    const float4 f = *(const float4*)(s + base + t4);
    bf16x4 o;
    o[0] = (bf16)f.x; o[1] = (bf16)f.y; o[2] = (bf16)f.z; o[3] = (bf16)f.w;
    *(bf16x4*)(dst + (size_t)blk * 1024 + t4) = o;
}

// ---------------------------------------------------------------------------
// Standalone LN (LN2).
// ---------------------------------------------------------------------------
__global__ __launch_bounds__(256) void ln_kernel(const float* __restrict__ xin,
                                                 bf16* __restrict__ out,
                                                 const float* __restrict__ gamma,
                                                 const float* __restrict__ beta) {
    __shared__ float red[8];
    ln_row(xin, out, blockIdx.x, threadIdx.x, gamma, beta, red);
}

// ---------------------------------------------------------------------------
// gemm_r3w8: RING-3 LDS 128x128/BK=32, 8 waves (r10-verified: occ 41%,
// 0 conflicts, VGPR 40). Used for QKV (EPI 4) and FFN1 (EPI 2) where
// 48 KiB keeps 3 blocks/CU.
//   iter t: issue STAGE(t+2) -> ds_read/MFMA tile t -> vmcnt(2) -> s_barrier.
// XOR bank swizzle: staging (row, slot c) fetches global chunk
// c ^ ((row>>1)&3); readers fetch phys chunk quad ^ ((row>>1)&3).
// ---------------------------------------------------------------------------
#define STAGE(tt, bi)                                              \
    do {                                                           \
        const int _k0 = (tt) << 5;                                 \
        load16_lds(Ap + _k0, &As[bi][tid * 8]);                    \
        load16_lds(Bp + _k0, &Bs[bi][tid * 8]);                    \
    } while (0)

template <int EPI>
__global__ __launch_bounds__(512, 4) void gemm_r3w8(const bf16* __restrict__ A,
                                                    const bf16* __restrict__ B,
                                                    int N, int K, int ldk,
                                                    bf16* __restrict__ outb,
                                                    float* __restrict__ outf,
                                                    const float* __restrict__ bias,
                                                    const float* __restrict__ resf,
                                                    bf16* __restrict__ qk,
                                                    bf16* __restrict__ vt) {
    __shared__ alignas(16) bf16 As[3][128 * 32];
    __shared__ alignas(16) bf16 Bs[3][128 * 32];
    const int tid = threadIdx.x;
    const int bm = blockIdx.x, bn = blockIdx.y;
    const int wave = tid >> 6, lane = tid & 63;
    const int wm = (wave >> 2) * 64, wn = (wave & 3) * 32;   // 2M x 4N
    const int l16 = lane & 15, quad = lane >> 4;

    f32x4 acc[4][2] = {};

    const size_t koff = (size_t)blockIdx.z * K;
    const int row0 = tid >> 2, ch0 = tid & 3;        // 512 thr: 128 rows x 4 ch
    const int gch = ch0 ^ ((row0 >> 1) & 3);         // source-permuted chunk
    const bf16* Ap = A + (size_t)(bm * 128 + row0) * ldk + koff + gch * 8;
    const bf16* Bp = B + (size_t)(bn * 128 + row0) * ldk + koff + gch * 8;

    const int nt = K >> 5;

    STAGE(0, 0);
    STAGE(1, 1);
    asm volatile("s_waitcnt vmcnt(2)" ::: "memory");
    __builtin_amdgcn_s_barrier();
    asm volatile("" ::: "memory");

    int i0 = 0, i1 = 1, i2 = 2;
    for (int t = 0; t < nt; ++t) {
        if (t + 2 < nt) STAGE(t + 2, i2);

        bf16x8 af[4], bfr[2];
#pragma unroll
        for (int i = 0; i < 4; i++) {
            const int ra = wm + i * 16 + l16;
            af[i] = *(const bf16x8*)(&As[i0][ra * 32 + (quad ^ ((ra >> 1) & 3)) * 8]);
        }
#pragma unroll
        for (int j = 0; j < 2; j++) {
            const int rb = wn + j * 16 + l16;
            bfr[j] = *(const bf16x8*)(&Bs[i0][rb * 32 + (quad ^ ((rb >> 1) & 3)) * 8]);
        }
        __builtin_amdgcn_s_setprio(1);
#pragma unroll
        for (int i = 0; i < 4; i++)
#pragma unroll
            for (int j = 0; j < 2; j++) acc[i][j] = mfma16(af[i], bfr[j], acc[i][j]);
        __builtin_amdgcn_s_setprio(0);

        if (t + 2 < nt) {
            asm volatile("s_waitcnt vmcnt(2)" ::: "memory");
        } else if (t + 1 < nt) {
            asm volatile("s_waitcnt vmcnt(0)" ::: "memory");
        }
        if (t + 1 < nt) {
            __builtin_amdgcn_s_barrier();
            asm volatile("" ::: "memory");
        }
        const int tmp = i0; i0 = i1; i1 = i2; i2 = tmp;
    }

#pragma unroll
    for (int i = 0; i < 4; i++) {
#pragma unroll
        for (int j = 0; j < 2; j++) {
            const int gr0 = bm * 128 + wm + i * 16 + quad * 4;
            const int gc = bn * 128 + wn + j * 16 + l16;
            float bv = 0.0f;
            if (EPI == 2) bv = bias[gc];
            if (EPI == 5 && bias && blockIdx.z == 0) bv = bias[gc];
            if (EPI == 4 && gc >= 2048) {
                const int n = gc - 2048;
                const int hh = n >> 6, dd = n & 63;
                const int bb = gr0 >> 11, ss = gr0 & 2047;
                bf16x4 pk;
#pragma unroll
                for (int r = 0; r < 4; r++) pk[r] = (bf16)acc[i][j][r];
                *(bf16x4*)(vt + ((size_t)((bb * 16 + hh) * 64 + dd)) * 2048 + ss) = pk;
            } else {
#pragma unroll
                for (int r = 0; r < 4; r++) {
                    const float v = acc[i][j][r];
                    const size_t idx = (size_t)(gr0 + r) * N + gc;
                    if (EPI == 1) {
                        outf[idx] = v + resf[idx];
                    } else if (EPI == 2) {
                        outb[idx] = (bf16)gelu_fast(v + bv);
                    } else if (EPI == 5) {
                        atomicAdd(&outf[idx], v + bv);
                    } else {
                        qk[(size_t)(gr0 + r) * 2048 + gc] = (bf16)v;
                    }
                }
            }
        }
    }
}

// ---------------------------------------------------------------------------
// gemm_r4w8: RING-4 variant (64 KiB LDS, 2-iteration prefetch window).
// iter t: issue STAGE(t+3) -> compute tile t -> counted wait:
//   t+3<nt: vmcnt(4) (stages t+2,t+3 in flight; t+1 landed)
//   t+2<nt: vmcnt(2) (stage t+2 in flight)
//   t+1<nt: vmcnt(0) (last prefetched tile)
// -> s_barrier. Write-after-read: STAGE(t+3) targets the buffer of tile t-1,
// whose reads finished before iter t-1's closing barrier.
// Used for FFN2 (grid 2/CU — LDS allows 2, no residency loss) and out-proj
// (1 block/CU — deep window is the only latency cover available).
// ---------------------------------------------------------------------------
template <int EPI>
__global__ __launch_bounds__(512, 2) void gemm_r4w8(const bf16* __restrict__ A,
                                                    const bf16* __restrict__ B,
                                                    int N, int K, int ldk,
                                                    bf16* __restrict__ outb,
                                                    float* __restrict__ outf,
                                                    const float* __restrict__ bias,
                                                    const float* __restrict__ resf,
                                                    bf16* __restrict__ qk,
                                                    bf16* __restrict__ vt) {
    __shared__ alignas(16) bf16 As[4][128 * 32];
    __shared__ alignas(16) bf16 Bs[4][128 * 32];
    const int tid = threadIdx.x;
    const int bm = blockIdx.x, bn = blockIdx.y;
    const int wave = tid >> 6, lane = tid & 63;
    const int wm = (wave >> 2) * 64, wn = (wave & 3) * 32;   // 2M x 4N
    const int l16 = lane & 15, quad = lane >> 4;

    f32x4 acc[4][2] = {};

    const size_t koff = (size_t)blockIdx.z * K;
    const int row0 = tid >> 2, ch0 = tid & 3;
    const int gch = ch0 ^ ((row0 >> 1) & 3);
    const bf16* Ap = A + (size_t)(bm * 128 + row0) * ldk + koff + gch * 8;
    const bf16* Bp = B + (size_t)(bn * 128 + row0) * ldk + koff + gch * 8;

    const int nt = K >> 5;                   // >= 4 for all users (32 / 64)

    STAGE(0, 0);
    STAGE(1, 1);
    STAGE(2, 2);
    asm volatile("s_waitcnt vmcnt(4)" ::: "memory");
    __builtin_amdgcn_s_barrier();
    asm volatile("" ::: "memory");

    int i0 = 0, i1 = 1, i2 = 2, i3 = 3;      // i0=compute, i3=stage dest
    for (int t = 0; t < nt; ++t) {
        if (t + 3 < nt) STAGE(t + 3, i3);

        bf16x8 af[4], bfr[2];
#pragma unroll
        for (int i = 0; i < 4; i++) {
            const int ra = wm + i * 16 + l16;
            af[i] = *(const bf16x8*)(&As[i0][ra * 32 + (quad ^ ((ra >> 1) & 3)) * 8]);
        }
#pragma unroll
        for (int j = 0; j < 2; j++) {
            const int rb = wn + j * 16 + l16;
            bfr[j] = *(const bf16x8*)(&Bs[i0][rb * 32 + (quad ^ ((rb >> 1) & 3)) * 8]);
        }
        __builtin_amdgcn_s_setprio(1);
#pragma unroll
        for (int i = 0; i < 4; i++)
#pragma unroll
            for (int j = 0; j < 2; j++) acc[i][j] = mfma16(af[i], bfr[j], acc[i][j]);
        __builtin_amdgcn_s_setprio(0);

        if (t + 3 < nt) {
            asm volatile("s_waitcnt vmcnt(4)" ::: "memory");
        } else if (t + 2 < nt) {
            asm volatile("s_waitcnt vmcnt(2)" ::: "memory");
        } else if (t + 1 < nt) {
            asm volatile("s_waitcnt vmcnt(0)" ::: "memory");
        }
        if (t + 1 < nt) {
            __builtin_amdgcn_s_barrier();
            asm volatile("" ::: "memory");
        }
        const int tmp = i0; i0 = i1; i1 = i2; i2 = i3; i3 = tmp;
    }

#pragma unroll
    for (int i = 0; i < 4; i++) {
#pragma unroll
        for (int j = 0; j < 2; j++) {
            const int gr0 = bm * 128 + wm + i * 16 + quad * 4;
            const int gc = bn * 128 + wn + j * 16 + l16;
            float bv = 0.0f;
            if (EPI == 5 && bias && blockIdx.z == 0) bv = bias[gc];
#pragma unroll
            for (int r = 0; r < 4; r++) {
                const float v = acc[i][j][r];
                const size_t idx = (size_t)(gr0 + r) * N + gc;
                if (EPI == 1) {
                    outf[idx] = v + resf[idx];
                } else if (EPI == 5) {
                    atomicAdd(&outf[idx], v + bv);
                } else {
                    outb[idx] = (bf16)v;
                }
            }
        }
    }
}
#undef STAGE

// ---------------------------------------------------------------------------
// Causal flash attention v3 — r5-exact body (verified ~55us).
// Fixed-shift softmax (shift=12; exact softmax, no online max/rescale).
// ---------------------------------------------------------------------------
__global__ __launch_bounds__(256, 4) void flash_attn(const bf16* __restrict__ qk,
                                                     const bf16* __restrict__ vt,
                                                     bf16* __restrict__ attn) {
    __shared__ alignas(16) bf16 Ks[64 * 72];
    __shared__ alignas(16) bf16 Vs[64 * 72];
    __shared__ alignas(16) bf16 Ps[4][16 * 72];
    const int tid = threadIdx.x;
    const int wave = tid >> 6, lane = tid & 63;
    const int l16 = lane & 15, quad = lane >> 4;
    const int bh = blockIdx.x;
    const int qt = 31 - blockIdx.y;
    const int b = bh >> 4, h = bh & 15;
    const int q0w = qt * 64 + wave * 16;
    const bf16* qkb = qk + (size_t)b * 2048 * 2048;
    const bf16* vtb = vt + (size_t)bh * 64 * 2048;

    bf16x8 qf[2];
#pragma unroll
    for (int c = 0; c < 2; c++) {
        bf16x8 v = *(const bf16x8*)(qkb + (size_t)(q0w + l16) * 2048 +
                                    h * 64 + c * 32 + quad * 8);
#pragma unroll
        for (int e = 0; e < 8; e++) v[e] = (bf16)((float)v[e] * 0.125f);
        qf[c] = v;
    }

    float lsum[4] = {0.0f, 0.0f, 0.0f, 0.0f};
    f32x4 o[4] = {};

    const int ntiles = qt + 1;
    for (int t = 0; t < ntiles; t++) {
        const int k0 = t * 64;
#pragma unroll
        for (int i = 0; i < 2; i++) {
            const int r = i * 32 + (tid >> 3), ch = tid & 7;
            *(uint4*)(&Ks[r * 72 + ch * 8]) =
                *(const uint4*)(qkb + (size_t)(k0 + r) * 2048 + 1024 + h * 64 + ch * 8);
            *(uint4*)(&Vs[r * 72 + ch * 8]) =
                *(const uint4*)(vtb + (size_t)r * 2048 + k0 + ch * 8);
        }
        __syncthreads();
        f32x4 s[4];
        __builtin_amdgcn_s_setprio(1);
#pragma unroll
        for (int kt = 0; kt < 4; kt++) {
            const bf16x8 k0f = *(const bf16x8*)(&Ks[(kt * 16 + l16) * 72 + quad * 8]);
            const bf16x8 k1f = *(const bf16x8*)(&Ks[(kt * 16 + l16) * 72 + 32 + quad * 8]);
            s[kt] = mfma16(qf[1], k1f, mfma16(qf[0], k0f, (f32x4){0, 0, 0, 0}));
        }
        __builtin_amdgcn_s_setprio(0);
        const bool need_mask = (t == ntiles - 1);
#pragma unroll
        for (int r = 0; r < 4; r++) {
            const int qrow = q0w + quad * 4 + r;
            float e0 = exp2f(fmaf(s[0][r], LOG2E, NSHIFT));
            float e1 = exp2f(fmaf(s[1][r], LOG2E, NSHIFT));
            float e2 = exp2f(fmaf(s[2][r], LOG2E, NSHIFT));
            float e3 = exp2f(fmaf(s[3][r], LOG2E, NSHIFT));
            if (need_mask) {
                if (k0 + l16 > qrow) e0 = 0.0f;
                if (k0 + 16 + l16 > qrow) e1 = 0.0f;
                if (k0 + 32 + l16 > qrow) e2 = 0.0f;
                if (k0 + 48 + l16 > qrow) e3 = 0.0f;
            }
            lsum[r] += (e0 + e1) + (e2 + e3);
            bf16* pp = &Ps[wave][(quad * 4 + r) * 72];
            pp[l16] = (bf16)e0;
            pp[16 + l16] = (bf16)e1;
            pp[32 + l16] = (bf16)e2;
            pp[48 + l16] = (bf16)e3;
        }
        // PV (Ps is per-wave private; lgkmcnt handles write->read in-wave)
        __builtin_amdgcn_s_setprio(1);
#pragma unroll
        for (int c = 0; c < 2; c++) {
            const bf16x8 pf = *(const bf16x8*)(&Ps[wave][l16 * 72 + c * 32 + quad * 8]);
#pragma unroll
            for (int dt = 0; dt < 4; dt++) {
                const bf16x8 vf =
                    *(const bf16x8*)(&Vs[(dt * 16 + l16) * 72 + c * 32 + quad * 8]);
                o[dt] = mfma16(pf, vf, o[dt]);
            }
        }
        __builtin_amdgcn_s_setprio(0);
        __syncthreads();
    }

    // epilogue: reduce l over the 16 lanes of each quad (bits 0-3)
#pragma unroll
    for (int r = 0; r < 4; r++) {
#pragma unroll
        for (int off = 1; off < 16; off <<= 1) lsum[r] += __shfl_xor(lsum[r], off);
        lsum[r] = 1.0f / fmaxf(lsum[r], 1e-30f);
    }
    bf16* ob = attn + (size_t)b * 2048 * 1024;
#pragma unroll
    for (int dt = 0; dt < 4; dt++)
#pragma unroll
        for (int r = 0; r < 4; r++) {
            const int q = q0w + quad * 4 + r;
            ob[(size_t)q * 1024 + h * 64 + dt * 16 + l16] = (bf16)(o[dt][r] * lsum[r]);
        }
}

// ---------------------------------------------------------------------------
extern "C" void kernel_launch(void* const* d_in, const int* in_sizes, int n_in,
                              void* d_out, int out_size, void* d_ws, size_t ws_size,
                              hipStream_t stream) {
    const float* x    = (const float*)d_in[0];
    const float* Wqkv = (const float*)d_in[2];
    const float* Wout = (const float*)d_in[3];
    const float* W1   = (const float*)d_in[4];
    const float* b1   = (const float*)d_in[5];
    const float* W2   = (const float*)d_in[6];
    const float* b2   = (const float*)d_in[7];
    const float* g1   = (const float*)d_in[8];
    const float* be1  = (const float*)d_in[9];
    const float* g2   = (const float*)d_in[10];
    const float* be2  = (const float*)d_in[11];

    char* ws = (char*)d_ws;
    bf16* Wb     = (bf16*)(ws);                 // all 4 weights, contiguous 24 MiB
    bf16* Wqkv_b = (bf16*)(ws);
    bf16* Wout_b = (bf16*)(ws + (6u << 20));
    bf16* W1_b   = (bf16*)(ws + (8u << 20));
    bf16* W2_b   = (bf16*)(ws + (16u << 20));
    bf16* h      = (bf16*)(ws + (24u << 20));
    bf16* qkbuf  = (bf16*)(ws + (32u << 20));
    bf16* vtbuf  = (bf16*)(ws + (48u << 20));
    bf16* attn   = (bf16*)(ws + (56u << 20));
    bf16* act    = (bf16*)(ws + (32u << 20));   // aliases qk/vt/attn post-attention
    float* x2    = (float*)d_out;               // residual stream lives in d_out

    // 0+1) weights fp32->bf16 AND h = LN1(x), one launch
    cvt4_ln_kernel<<<16384, 256, 0, stream>>>(Wqkv, Wout, W1, W2, Wb,
                                              x, h, g1, be1);
    // 2) qkv = h @ Wqkv^T -> qk rows + V^T   (ring-3, 8 waves)
    gemm_r3w8<4><<<dim3(32, 24), 512, 0, stream>>>(h, Wqkv_b, 3072, 1024, 1024,
                                                   nullptr, nullptr, nullptr, nullptr,
                                                   qkbuf, vtbuf);
    // 3) attn = causal_flash(qk, vt)   (r5-exact)
    flash_attn<<<dim3(32, 32), 256, 0, stream>>>(qkbuf, vtbuf, attn);
    // 4) x2 = attn @ Wout^T + x   (ring-4, 8 waves; 1 block/CU -> deep window)
    gemm_r4w8<1><<<dim3(32, 8), 512, 0, stream>>>(attn, Wout_b, 1024, 1024, 1024,
                                                  nullptr, x2, nullptr, x, nullptr, nullptr);
    // 5) h = LN2(x2)
    ln_kernel<<<4096, 256, 0, stream>>>(x2, h, g2, be2);
    // 6) act = gelu_fast(h @ W1^T + b1)   (ring-3, 8 waves)
    gemm_r3w8<2><<<dim3(32, 32), 512, 0, stream>>>(h, W1_b, 4096, 1024, 1024,
                                                   act, nullptr, b1, nullptr, nullptr, nullptr);
    // 7) out += act @ W2^T + b2   (ring-4, 8 waves, split-K=2, atomicAdd)
    gemm_r4w8<5><<<dim3(32, 8, 2), 512, 0, stream>>>(act, W2_b, 1024, 2048, 4096,
                                                     nullptr, x2, b2, nullptr, nullptr, nullptr);
}